// Round 1
// baseline (25757.672 us; speedup 1.0000x reference)
//
#include <hip/hip_runtime.h>

// LSTMDecoder: B=1024, L=128, H=256, OUT=64, T=256, 2 layers.
// Design: 64 workgroups x 256 threads (4 waves). Each WG owns 16 batch rows
// end-to-end (no inter-WG communication). Per step, each wave computes
// 16 n-tiles of gates via mfma_f32_16x16x32_bf16 streaming bf16 weights from
// L2, does the c/h pointwise update entirely in registers (i/f/g/o tiles for
// the same h-index are co-resident in the same lane), and round-trips h
// through double-buffered LDS only for the A-fragment re-layout.
// Weights pre-converted fp32->bf16 into d_ws by a small kernel.

typedef float f32x4 __attribute__((ext_vector_type(4)));
typedef short bf16x8 __attribute__((ext_vector_type(8)));
typedef unsigned short u16;

// bf16 workspace layout (element offsets)
#define OFF_LH   0          // [512][128]
#define OFF_LC   65536      // [512][128]
#define OFF_IH0  131072     // [1024][128]
#define OFF_HH0  262144     // [1024][256]
#define OFF_IH1  524288     // [1024][256]
#define OFF_HH1  786432     // [1024][256]
#define OFF_OUT  1048576    // [64][256]

__device__ __forceinline__ u16 f2bf(float x){
  unsigned u = __builtin_bit_cast(unsigned, x);
  unsigned r = (u + 0x7fffu + ((u >> 16) & 1u)) >> 16;  // RNE
  return (u16)r;
}

__global__ __launch_bounds__(256) void convert_bf16(const float* __restrict__ src,
                                                    u16* __restrict__ dst, int n){
  int i = blockIdx.x * 256 + threadIdx.x;
  if (i < n) dst[i] = f2bf(src[i]);
}

__device__ __forceinline__ f32x4 mfma16(bf16x8 a, bf16x8 b, f32x4 c){
  return __builtin_amdgcn_mfma_f32_16x16x32_bf16(a, b, c, 0, 0, 0);
}

__device__ __forceinline__ bf16x8 ld8(const u16* p){ return *(const bf16x8*)p; }

__device__ __forceinline__ float sigm(float x){ return 1.f/(1.f + __expf(-x)); }
// tanh without inf/inf NaN at |x| large
__device__ __forceinline__ float tanh_f(float x){ return 1.f - 2.f/(__expf(2.f*x) + 1.f); }

#define HSTRIDE 264   // 256 + 8 bf16 pad (16B) to break power-of-2 LDS strides

__global__ __launch_bounds__(256, 1) void lstm_fused(
    const float* __restrict__ latent,
    const float* __restrict__ b_lh, const float* __restrict__ b_lc,
    const float* __restrict__ b_ih0, const float* __restrict__ b_hh0,
    const float* __restrict__ b_ih1, const float* __restrict__ b_hh1,
    const float* __restrict__ b_out,
    const u16* __restrict__ ws,
    float* __restrict__ out)
{
  __shared__ __attribute__((aligned(16))) u16 lat_s[16*136];
  __shared__ __attribute__((aligned(16))) u16 h0_s[2][16*HSTRIDE];
  __shared__ __attribute__((aligned(16))) u16 h1_s[2][16*HSTRIDE];

  const u16* __restrict__ w_lh  = ws + OFF_LH;
  const u16* __restrict__ w_lc  = ws + OFF_LC;
  const u16* __restrict__ w_ih0 = ws + OFF_IH0;
  const u16* __restrict__ w_hh0 = ws + OFF_HH0;
  const u16* __restrict__ w_ih1 = ws + OFF_IH1;
  const u16* __restrict__ w_hh1 = ws + OFF_HH1;
  const u16* __restrict__ w_out = ws + OFF_OUT;

  const int tid  = threadIdx.x;
  const int w    = tid >> 6;      // wave 0..3
  const int lane = tid & 63;
  const int col  = lane & 15;     // MFMA n / m index
  const int quad = lane >> 4;     // MFMA k-group / row-group
  const int bbase = blockIdx.x * 16;
  const int lo256 = col*256 + quad*8;  // lane offset into a K=256 row-major tile
  const int lo128 = col*128 + quad*8;  // lane offset into a K=128 row-major tile
  const int hrow  = quad*4;            // acc row base (b index within tile)

  // ---- stage latent (bf16) ----
  for (int i = tid; i < 16*128; i += 256){
    int b = i >> 7, k = i & 127;
    lat_s[b*136 + k] = f2bf(latent[(bbase + b)*128 + k]);
  }
  __syncthreads();

  bf16x8 latA[4];
  #pragma unroll
  for (int kt = 0; kt < 4; ++kt)
    latA[kt] = ld8(&lat_s[col*136 + kt*32 + quad*8]);

  // ---- gx0 = latent @ w_ih0^T + b_ih0 + b_hh0 (kept in regs, reused all steps) ----
  f32x4 gx0[4][4];
  #pragma unroll
  for (int jt = 0; jt < 4; ++jt){
    #pragma unroll
    for (int gi = 0; gi < 4; ++gi){
      const int nt = gi*16 + w*4 + jt;
      const int n  = nt*16 + col;
      float bias = b_ih0[n] + b_hh0[n];
      f32x4 a = {bias, bias, bias, bias};
      #pragma unroll
      for (int kt = 0; kt < 4; ++kt)
        a = mfma16(latA[kt], ld8(w_ih0 + nt*2048 + kt*32 + lo128), a);
      gx0[jt][gi] = a;
    }
  }

  // ---- initial h/c for both layers ----
  float c0[4][4], c1[4][4];
  #pragma unroll
  for (int jt = 0; jt < 4; ++jt){
    const int ntl = w*4 + jt;     // layer-0 h-tile = rows [ntl*16,..) of w_lh/w_lc
    const int n0  = ntl*16 + col;
    { float bias = b_lc[n0]; f32x4 a = {bias,bias,bias,bias};
      #pragma unroll
      for (int kt=0;kt<4;++kt) a = mfma16(latA[kt], ld8(w_lc + ntl*2048 + kt*32 + lo128), a);
      #pragma unroll
      for (int r=0;r<4;++r) c0[jt][r] = a[r]; }
    { float bias = b_lc[256 + n0]; f32x4 a = {bias,bias,bias,bias};
      #pragma unroll
      for (int kt=0;kt<4;++kt) a = mfma16(latA[kt], ld8(w_lc + (16+ntl)*2048 + kt*32 + lo128), a);
      #pragma unroll
      for (int r=0;r<4;++r) c1[jt][r] = a[r]; }
    { float bias = b_lh[n0]; f32x4 a = {bias,bias,bias,bias};
      #pragma unroll
      for (int kt=0;kt<4;++kt) a = mfma16(latA[kt], ld8(w_lh + ntl*2048 + kt*32 + lo128), a);
      #pragma unroll
      for (int r=0;r<4;++r) h0_s[0][(hrow+r)*HSTRIDE + ntl*16 + col] = f2bf(a[r]); }
    { float bias = b_lh[256 + n0]; f32x4 a = {bias,bias,bias,bias};
      #pragma unroll
      for (int kt=0;kt<4;++kt) a = mfma16(latA[kt], ld8(w_lh + (16+ntl)*2048 + kt*32 + lo128), a);
      #pragma unroll
      for (int r=0;r<4;++r) h1_s[0][(hrow+r)*HSTRIDE + ntl*16 + col] = f2bf(a[r]); }
  }

  // ---- persistent out-proj fragments + biases ----
  bf16x8 wof[8];
  #pragma unroll
  for (int kt=0;kt<8;++kt) wof[kt] = ld8(w_out + w*4096 + kt*32 + lo256);
  const float bout = b_out[w*16 + col];

  float bias1[4][4];
  #pragma unroll
  for (int jt=0;jt<4;++jt)
    #pragma unroll
    for (int gi=0;gi<4;++gi){
      int n = (gi*16 + w*4 + jt)*16 + col;
      bias1[jt][gi] = b_ih1[n] + b_hh1[n];
    }

  __syncthreads();
  bf16x8 h0A[8], h1A[8];
  #pragma unroll
  for (int kt=0;kt<8;++kt) h0A[kt] = ld8(&h0_s[0][col*HSTRIDE + kt*32 + quad*8]);
  #pragma unroll
  for (int kt=0;kt<8;++kt) h1A[kt] = ld8(&h1_s[0][col*HSTRIDE + kt*32 + quad*8]);

  int wb = 1;

  for (int t = 0; t < 256; ++t){
    // ======== layer 0: gates = gx0 + h0 @ w_hh0^T ========
    f32x4 acc[4][4];
    #pragma unroll
    for (int jt=0;jt<4;++jt)
      #pragma unroll
      for (int gi=0;gi<4;++gi) acc[jt][gi] = gx0[jt][gi];
    #pragma unroll
    for (int kt=0;kt<8;++kt){
      bf16x8 bb[16];
      #pragma unroll
      for (int jt=0;jt<4;++jt)
        #pragma unroll
        for (int gi=0;gi<4;++gi)
          bb[jt*4+gi] = ld8(w_hh0 + (gi*16 + w*4 + jt)*4096 + kt*32 + lo256);
      #pragma unroll
      for (int jt=0;jt<4;++jt)
        #pragma unroll
        for (int gi=0;gi<4;++gi)
          acc[jt][gi] = mfma16(h0A[kt], bb[jt*4+gi], acc[jt][gi]);
    }
    // pointwise (i,f,g,o for same h-index live in this lane)
    #pragma unroll
    for (int jt=0;jt<4;++jt){
      #pragma unroll
      for (int r=0;r<4;++r){
        float ii = sigm(acc[jt][0][r]);
        float ff = sigm(acc[jt][1][r]);
        float gg = tanh_f(acc[jt][2][r]);
        float oo = sigm(acc[jt][3][r]);
        float c = ff*c0[jt][r] + ii*gg;
        c0[jt][r] = c;
        float h = oo * tanh_f(c);
        h0_s[wb][(hrow+r)*HSTRIDE + (w*4+jt)*16 + col] = f2bf(h);
      }
    }
    __syncthreads();
    #pragma unroll
    for (int kt=0;kt<8;++kt) h0A[kt] = ld8(&h0_s[wb][col*HSTRIDE + kt*32 + quad*8]);

    // ======== layer 1: gates = bias1 + h0(t) @ w_ih1^T + h1(t-1) @ w_hh1^T ========
    #pragma unroll
    for (int jt=0;jt<4;++jt)
      #pragma unroll
      for (int gi=0;gi<4;++gi){
        float b1 = bias1[jt][gi];
        f32x4 a = {b1,b1,b1,b1};
        acc[jt][gi] = a;
      }
    #pragma unroll
    for (int kt=0;kt<8;++kt){
      bf16x8 bb[16];
      #pragma unroll
      for (int jt=0;jt<4;++jt)
        #pragma unroll
        for (int gi=0;gi<4;++gi)
          bb[jt*4+gi] = ld8(w_ih1 + (gi*16 + w*4 + jt)*4096 + kt*32 + lo256);
      #pragma unroll
      for (int jt=0;jt<4;++jt)
        #pragma unroll
        for (int gi=0;gi<4;++gi)
          acc[jt][gi] = mfma16(h0A[kt], bb[jt*4+gi], acc[jt][gi]);
    }
    #pragma unroll
    for (int kt=0;kt<8;++kt){
      bf16x8 bb[16];
      #pragma unroll
      for (int jt=0;jt<4;++jt)
        #pragma unroll
        for (int gi=0;gi<4;++gi)
          bb[jt*4+gi] = ld8(w_hh1 + (gi*16 + w*4 + jt)*4096 + kt*32 + lo256);
      #pragma unroll
      for (int jt=0;jt<4;++jt)
        #pragma unroll
        for (int gi=0;gi<4;++gi)
          acc[jt][gi] = mfma16(h1A[kt], bb[jt*4+gi], acc[jt][gi]);
    }
    #pragma unroll
    for (int jt=0;jt<4;++jt){
      #pragma unroll
      for (int r=0;r<4;++r){
        float ii = sigm(acc[jt][0][r]);
        float ff = sigm(acc[jt][1][r]);
        float gg = tanh_f(acc[jt][2][r]);
        float oo = sigm(acc[jt][3][r]);
        float c = ff*c1[jt][r] + ii*gg;
        c1[jt][r] = c;
        float h = oo * tanh_f(c);
        h1_s[wb][(hrow+r)*HSTRIDE + (w*4+jt)*16 + col] = f2bf(h);
      }
    }
    __syncthreads();
    #pragma unroll
    for (int kt=0;kt<8;++kt) h1A[kt] = ld8(&h1_s[wb][col*HSTRIDE + kt*32 + quad*8]);

    // ======== output projection: out[b,t,:] = h1(t) @ w_out^T + b_out ========
    f32x4 oacc = {bout, bout, bout, bout};
    #pragma unroll
    for (int kt=0;kt<8;++kt) oacc = mfma16(h1A[kt], wof[kt], oacc);
    const int o = w*16 + col;
    #pragma unroll
    for (int r=0;r<4;++r){
      int b = bbase + hrow + r;
      out[(b*256 + t)*64 + o] = oacc[r];
    }
    wb ^= 1;
  }
}

extern "C" void kernel_launch(void* const* d_in, const int* in_sizes, int n_in,
                              void* d_out, int out_size, void* d_ws, size_t ws_size,
                              hipStream_t stream)
{
  (void)in_sizes; (void)n_in; (void)out_size; (void)ws_size;
  const float* latent = (const float*)d_in[0];
  const float* w_lh   = (const float*)d_in[1];
  const float* b_lh   = (const float*)d_in[2];
  const float* w_lc   = (const float*)d_in[3];
  const float* b_lc   = (const float*)d_in[4];
  const float* w_ih0  = (const float*)d_in[5];
  const float* w_hh0  = (const float*)d_in[6];
  const float* b_ih0  = (const float*)d_in[7];
  const float* b_hh0  = (const float*)d_in[8];
  const float* w_ih1  = (const float*)d_in[9];
  const float* w_hh1  = (const float*)d_in[10];
  const float* b_ih1  = (const float*)d_in[11];
  const float* b_hh1  = (const float*)d_in[12];
  const float* w_out  = (const float*)d_in[13];
  const float* b_out  = (const float*)d_in[14];
  u16* ws = (u16*)d_ws;
  float* out = (float*)d_out;

  auto cvt = [&](const float* src, int off, int n){
    convert_bf16<<<dim3((n + 255)/256), dim3(256), 0, stream>>>(src, ws + off, n);
  };
  cvt(w_lh,  OFF_LH,  512*128);
  cvt(w_lc,  OFF_LC,  512*128);
  cvt(w_ih0, OFF_IH0, 1024*128);
  cvt(w_hh0, OFF_HH0, 1024*256);
  cvt(w_ih1, OFF_IH1, 1024*256);
  cvt(w_hh1, OFF_HH1, 1024*256);
  cvt(w_out, OFF_OUT, 64*256);

  lstm_fused<<<dim3(64), dim3(256), 0, stream>>>(latent, b_lh, b_lc, b_ih0, b_hh0,
                                                 b_ih1, b_hh1, b_out, ws, out);
}

// Round 2
// 13984.030 us; speedup vs baseline: 1.8419x; 1.8419x over previous
//
#include <hip/hip_runtime.h>

// LSTMDecoder: B=1024, L=128, H=256, OUT=64, T=256, 2 layers.
// R2: 64 WGs x 512 threads (8 waves, 2 waves/SIMD). Each WG owns 16 batch
// rows; each wave owns 8 of 64 gate n-tiles (tiles g*16 + 2w + j, j=0..1).
// Weights pre-swizzled into MFMA B-fragment order so every B-fragment load
// is one contiguous 1KB wave-coalesced segment. Persistent state ~130 VGPR
// -> compiler can keep 8-load batches in flight (round-1 was vmcnt(0)
// serialized at 256 VGPR cap: 625 cyc/load * 384 loads/step = 100us/step).

typedef float f32x4 __attribute__((ext_vector_type(4)));
typedef short bf16x8 __attribute__((ext_vector_type(8)));
typedef unsigned short u16;

// bf16 workspace layout (element offsets), all matrices swizzled:
// elem[((nt*KB + kt)*64 + lane)*8 + j] = W[nt*16 + (lane&15)][kt*32 + (lane>>4)*8 + j]
#define OFF_LH   0          // 32 tiles, KB=4
#define OFF_LC   65536      // 32 tiles, KB=4
#define OFF_IH0  131072     // 64 tiles, KB=4
#define OFF_HH0  262144     // 64 tiles, KB=8
#define OFF_IH1  524288     // 64 tiles, KB=8
#define OFF_HH1  786432     // 64 tiles, KB=8
#define OFF_OUT  1048576    // 4 tiles,  KB=8

__device__ __forceinline__ u16 f2bf(float x){
  unsigned u = __builtin_bit_cast(unsigned, x);
  return (u16)((u + 0x7fffu + ((u >> 16) & 1u)) >> 16);  // RNE
}

__global__ __launch_bounds__(256) void convert_swizzle(
    const float* __restrict__ src, u16* __restrict__ dst,
    int ntiles, int kbshift)
{
  int idx = blockIdx.x * 256 + threadIdx.x;
  int kblocks = 1 << kbshift;
  int n = ntiles << (kbshift + 9);
  if (idx >= n) return;
  int j    = idx & 7;
  int lane = (idx >> 3) & 63;
  int t3   = idx >> 9;
  int kt   = t3 & (kblocks - 1);
  int nt   = t3 >> kbshift;
  int row  = nt * 16 + (lane & 15);
  int k    = kt * 32 + (lane >> 4) * 8 + j;
  dst[idx] = f2bf(src[row * (kblocks * 32) + k]);
}

__device__ __forceinline__ f32x4 mfma16(bf16x8 a, bf16x8 b, f32x4 c){
  return __builtin_amdgcn_mfma_f32_16x16x32_bf16(a, b, c, 0, 0, 0);
}
__device__ __forceinline__ bf16x8 ld8(const u16* p){ return *(const bf16x8*)p; }
__device__ __forceinline__ float sigm(float x){ return 1.f/(1.f + __expf(-x)); }
__device__ __forceinline__ float tanh_f(float x){ return 1.f - 2.f/(__expf(2.f*x) + 1.f); }

#define HSTRIDE 264   // 256 + 8 bf16 pad

__global__ __launch_bounds__(512, 2) void lstm_fused(
    const float* __restrict__ latent,
    const float* __restrict__ b_lh, const float* __restrict__ b_lc,
    const float* __restrict__ b_ih0, const float* __restrict__ b_hh0,
    const float* __restrict__ b_ih1, const float* __restrict__ b_hh1,
    const float* __restrict__ b_out,
    const u16* __restrict__ ws,
    float* __restrict__ out)
{
  __shared__ __attribute__((aligned(16))) u16 lat_s[16*136];
  __shared__ __attribute__((aligned(16))) u16 h0_s[2][16*HSTRIDE];
  __shared__ __attribute__((aligned(16))) u16 h1_s[2][16*HSTRIDE];

  const u16* __restrict__ w_lh  = ws + OFF_LH;
  const u16* __restrict__ w_lc  = ws + OFF_LC;
  const u16* __restrict__ w_ih0 = ws + OFF_IH0;
  const u16* __restrict__ w_hh0 = ws + OFF_HH0;
  const u16* __restrict__ w_ih1 = ws + OFF_IH1;
  const u16* __restrict__ w_hh1 = ws + OFF_HH1;
  const u16* __restrict__ w_out = ws + OFF_OUT;

  const int tid  = threadIdx.x;
  const int w    = tid >> 6;      // wave 0..7
  const int lane = tid & 63;
  const int col  = lane & 15;
  const int quad = lane >> 4;
  const int bbase = blockIdx.x * 16;
  const int hrow  = quad * 4;
  const int l8    = lane * 8;     // swizzled-layout lane offset (elements)

  // ---- stage latent (bf16) ----
  for (int i = tid; i < 16*128; i += 512){
    int b = i >> 7, k = i & 127;
    lat_s[b*136 + k] = f2bf(latent[(bbase + b)*128 + k]);
  }
  __syncthreads();

  bf16x8 latA[4];
  #pragma unroll
  for (int kt = 0; kt < 4; ++kt)
    latA[kt] = ld8(&lat_s[col*136 + kt*32 + quad*8]);

  // ---- gx0 = latent @ w_ih0^T + b_ih0 + b_hh0 (per-wave 8 tiles, in regs) ----
  f32x4 gx0[2][4];
  #pragma unroll
  for (int j = 0; j < 2; ++j){
    #pragma unroll
    for (int g = 0; g < 4; ++g){
      const int nt = g*16 + 2*w + j;
      const int n  = nt*16 + col;
      float bias = b_ih0[n] + b_hh0[n];
      f32x4 a = {bias, bias, bias, bias};
      #pragma unroll
      for (int kt = 0; kt < 4; ++kt)
        a = mfma16(latA[kt], ld8(w_ih0 + ((nt*4 + kt) << 9) + l8), a);
      gx0[j][g] = a;
    }
  }

  // ---- initial h/c for both layers (wave owns h-tiles 2w, 2w+1) ----
  float c0[2][4], c1[2][4];
  #pragma unroll
  for (int j = 0; j < 2; ++j){
    const int ntl = 2*w + j;
    const int n0  = ntl*16 + col;
    { float bias = b_lc[n0]; f32x4 a = {bias,bias,bias,bias};
      #pragma unroll
      for (int kt=0;kt<4;++kt) a = mfma16(latA[kt], ld8(w_lc + ((ntl*4+kt)<<9) + l8), a);
      #pragma unroll
      for (int r=0;r<4;++r) c0[j][r] = a[r]; }
    { float bias = b_lc[256 + n0]; f32x4 a = {bias,bias,bias,bias};
      #pragma unroll
      for (int kt=0;kt<4;++kt) a = mfma16(latA[kt], ld8(w_lc + (((16+ntl)*4+kt)<<9) + l8), a);
      #pragma unroll
      for (int r=0;r<4;++r) c1[j][r] = a[r]; }
    { float bias = b_lh[n0]; f32x4 a = {bias,bias,bias,bias};
      #pragma unroll
      for (int kt=0;kt<4;++kt) a = mfma16(latA[kt], ld8(w_lh + ((ntl*4+kt)<<9) + l8), a);
      #pragma unroll
      for (int r=0;r<4;++r) h0_s[0][(hrow+r)*HSTRIDE + ntl*16 + col] = f2bf(a[r]); }
    { float bias = b_lh[256 + n0]; f32x4 a = {bias,bias,bias,bias};
      #pragma unroll
      for (int kt=0;kt<4;++kt) a = mfma16(latA[kt], ld8(w_lh + (((16+ntl)*4+kt)<<9) + l8), a);
      #pragma unroll
      for (int r=0;r<4;++r) h1_s[0][(hrow+r)*HSTRIDE + ntl*16 + col] = f2bf(a[r]); }
  }

  float bias1[2][4];
  #pragma unroll
  for (int j=0;j<2;++j)
    #pragma unroll
    for (int g=0;g<4;++g){
      int n = (g*16 + 2*w + j)*16 + col;
      bias1[j][g] = b_ih1[n] + b_hh1[n];
    }
  const float bout = (w < 4) ? b_out[w*16 + col] : 0.f;

  __syncthreads();
  bf16x8 h0A[8], h1A[8];
  #pragma unroll
  for (int kt=0;kt<8;++kt) h0A[kt] = ld8(&h0_s[0][col*HSTRIDE + kt*32 + quad*8]);
  #pragma unroll
  for (int kt=0;kt<8;++kt) h1A[kt] = ld8(&h1_s[0][col*HSTRIDE + kt*32 + quad*8]);

  int wb = 1;

  for (int t = 0; t < 256; ++t){
    // ======== layer 0: gates = gx0 + h0 @ w_hh0^T ========
    f32x4 acc[2][4];
    #pragma unroll
    for (int j=0;j<2;++j)
      #pragma unroll
      for (int g=0;g<4;++g) acc[j][g] = gx0[j][g];
    #pragma unroll
    for (int kt=0;kt<8;++kt){
      bf16x8 bb[8];
      #pragma unroll
      for (int j=0;j<2;++j)
        #pragma unroll
        for (int g=0;g<4;++g)
          bb[j*4+g] = ld8(w_hh0 + (((g*16 + 2*w + j)*8 + kt) << 9) + l8);
      #pragma unroll
      for (int j=0;j<2;++j)
        #pragma unroll
        for (int g=0;g<4;++g)
          acc[j][g] = mfma16(h0A[kt], bb[j*4+g], acc[j][g]);
    }
    #pragma unroll
    for (int j=0;j<2;++j){
      #pragma unroll
      for (int r=0;r<4;++r){
        float ii = sigm(acc[j][0][r]);
        float ff = sigm(acc[j][1][r]);
        float gg = tanh_f(acc[j][2][r]);
        float oo = sigm(acc[j][3][r]);
        float c = ff*c0[j][r] + ii*gg;
        c0[j][r] = c;
        float h = oo * tanh_f(c);
        h0_s[wb][(hrow+r)*HSTRIDE + (2*w+j)*16 + col] = f2bf(h);
      }
    }
    __syncthreads();
    #pragma unroll
    for (int kt=0;kt<8;++kt) h0A[kt] = ld8(&h0_s[wb][col*HSTRIDE + kt*32 + quad*8]);

    // ======== layer 1: gates = bias1 + h0(t) @ w_ih1^T + h1(t-1) @ w_hh1^T ========
    #pragma unroll
    for (int j=0;j<2;++j)
      #pragma unroll
      for (int g=0;g<4;++g){
        float b1 = bias1[j][g];
        f32x4 a = {b1,b1,b1,b1};
        acc[j][g] = a;
      }
    #pragma unroll
    for (int kt=0;kt<8;++kt){
      bf16x8 bb[8];
      #pragma unroll
      for (int j=0;j<2;++j)
        #pragma unroll
        for (int g=0;g<4;++g)
          bb[j*4+g] = ld8(w_ih1 + (((g*16 + 2*w + j)*8 + kt) << 9) + l8);
      #pragma unroll
      for (int j=0;j<2;++j)
        #pragma unroll
        for (int g=0;g<4;++g)
          acc[j][g] = mfma16(h0A[kt], bb[j*4+g], acc[j][g]);
    }
    #pragma unroll
    for (int kt=0;kt<8;++kt){
      bf16x8 bb[8];
      #pragma unroll
      for (int j=0;j<2;++j)
        #pragma unroll
        for (int g=0;g<4;++g)
          bb[j*4+g] = ld8(w_hh1 + (((g*16 + 2*w + j)*8 + kt) << 9) + l8);
      #pragma unroll
      for (int j=0;j<2;++j)
        #pragma unroll
        for (int g=0;g<4;++g)
          acc[j][g] = mfma16(h1A[kt], bb[j*4+g], acc[j][g]);
    }
    #pragma unroll
    for (int j=0;j<2;++j){
      #pragma unroll
      for (int r=0;r<4;++r){
        float ii = sigm(acc[j][0][r]);
        float ff = sigm(acc[j][1][r]);
        float gg = tanh_f(acc[j][2][r]);
        float oo = sigm(acc[j][3][r]);
        float c = ff*c1[j][r] + ii*gg;
        c1[j][r] = c;
        float h = oo * tanh_f(c);
        h1_s[wb][(hrow+r)*HSTRIDE + (2*w+j)*16 + col] = f2bf(h);
      }
    }
    __syncthreads();
    #pragma unroll
    for (int kt=0;kt<8;++kt) h1A[kt] = ld8(&h1_s[wb][col*HSTRIDE + kt*32 + quad*8]);

    // ======== output projection (waves 0..3 only) ========
    if (w < 4){
      f32x4 oacc = {bout, bout, bout, bout};
      #pragma unroll
      for (int kt=0;kt<8;++kt)
        oacc = mfma16(h1A[kt], ld8(w_out + ((w*8 + kt) << 9) + l8), oacc);
      const int o = w*16 + col;
      #pragma unroll
      for (int r=0;r<4;++r){
        int b = bbase + hrow + r;
        out[(b*256 + t)*64 + o] = oacc[r];
      }
    }
    wb ^= 1;
  }
}

extern "C" void kernel_launch(void* const* d_in, const int* in_sizes, int n_in,
                              void* d_out, int out_size, void* d_ws, size_t ws_size,
                              hipStream_t stream)
{
  (void)in_sizes; (void)n_in; (void)out_size; (void)ws_size;
  const float* latent = (const float*)d_in[0];
  const float* w_lh   = (const float*)d_in[1];
  const float* b_lh   = (const float*)d_in[2];
  const float* w_lc   = (const float*)d_in[3];
  const float* b_lc   = (const float*)d_in[4];
  const float* w_ih0  = (const float*)d_in[5];
  const float* w_hh0  = (const float*)d_in[6];
  const float* b_ih0  = (const float*)d_in[7];
  const float* b_hh0  = (const float*)d_in[8];
  const float* w_ih1  = (const float*)d_in[9];
  const float* w_hh1  = (const float*)d_in[10];
  const float* b_ih1  = (const float*)d_in[11];
  const float* b_hh1  = (const float*)d_in[12];
  const float* w_out  = (const float*)d_in[13];
  const float* b_out  = (const float*)d_in[14];
  u16* ws = (u16*)d_ws;
  float* out = (float*)d_out;

  auto cvt = [&](const float* src, int off, int ntiles, int kbshift){
    int n = ntiles << (kbshift + 9);
    convert_swizzle<<<dim3((n + 255)/256), dim3(256), 0, stream>>>(src, ws + off, ntiles, kbshift);
  };
  cvt(w_lh,  OFF_LH,  32, 2);
  cvt(w_lc,  OFF_LC,  32, 2);
  cvt(w_ih0, OFF_IH0, 64, 2);
  cvt(w_hh0, OFF_HH0, 64, 3);
  cvt(w_ih1, OFF_IH1, 64, 3);
  cvt(w_hh1, OFF_HH1, 64, 3);
  cvt(w_out, OFF_OUT, 4, 3);

  lstm_fused<<<dim3(64), dim3(512), 0, stream>>>(latent, b_lh, b_lc, b_ih0, b_hh0,
                                                 b_ih1, b_hh1, b_out, ws, out);
}

// Round 4
// 11579.689 us; speedup vs baseline: 2.2244x; 1.2076x over previous
//
#include <hip/hip_runtime.h>

// LSTMDecoder: B=1024, L=128, H=256, OUT=64, T=256, 2 layers.
// R4: 64 WGs x 1024 threads (16 waves, 4 waves/SIMD). Wave w owns gate tiles
// {g*16+w} (g=0..3 <-> i,f,g,o) and h-tile w. Weight loads software-pipelined
// with ping-pong register buffers (Pa/Pb). Barriers are plain __syncthreads()
// — R3's lgkmcnt-only asm barrier caused a narrow race (absmax 3.5e-2); the
// vmcnt(0) drain it forces costs only ~2x600cyc/step (~130us total).
// h0/h1 LDS exchanges double-buffered. Per-WG per-step weight stream =
// 1.57 MB bf16 -> feed-BW floor ~10.7us/step ~2.7ms at 64 B/cyc/CU.

typedef float f32x4 __attribute__((ext_vector_type(4)));
typedef short bf16x8 __attribute__((ext_vector_type(8)));
typedef unsigned short u16;

// bf16 workspace layout (element offsets), swizzled:
// elem[((nt*KB + kt)*64 + lane)*8 + j] = W[nt*16 + (lane&15)][kt*32 + (lane>>4)*8 + j]
#define OFF_LH   0          // 32 tiles, KB=4
#define OFF_LC   65536      // 32 tiles, KB=4
#define OFF_IH0  131072     // 64 tiles, KB=4
#define OFF_HH0  262144     // 64 tiles, KB=8
#define OFF_IH1  524288     // 64 tiles, KB=8
#define OFF_HH1  786432     // 64 tiles, KB=8
#define OFF_OUT  1048576    // 4 tiles,  KB=8

__device__ __forceinline__ u16 f2bf(float x){
  unsigned u = __builtin_bit_cast(unsigned, x);
  return (u16)((u + 0x7fffu + ((u >> 16) & 1u)) >> 16);  // RNE
}

__global__ __launch_bounds__(256) void convert_swizzle(
    const float* __restrict__ src, u16* __restrict__ dst,
    int ntiles, int kbshift)
{
  int idx = blockIdx.x * 256 + threadIdx.x;
  int kblocks = 1 << kbshift;
  int n = ntiles << (kbshift + 9);
  if (idx >= n) return;
  int j    = idx & 7;
  int lane = (idx >> 3) & 63;
  int t3   = idx >> 9;
  int kt   = t3 & (kblocks - 1);
  int nt   = t3 >> kbshift;
  int row  = nt * 16 + (lane & 15);
  int k    = kt * 32 + (lane >> 4) * 8 + j;
  dst[idx] = f2bf(src[row * (kblocks * 32) + k]);
}

__device__ __forceinline__ f32x4 mfma16(bf16x8 a, bf16x8 b, f32x4 c){
  return __builtin_amdgcn_mfma_f32_16x16x32_bf16(a, b, c, 0, 0, 0);
}
__device__ __forceinline__ bf16x8 ld8(const u16* p){ return *(const bf16x8*)p; }
__device__ __forceinline__ float sigm(float x){ return 1.f/(1.f + __expf(-x)); }
__device__ __forceinline__ float tanh_f(float x){ return 1.f - 2.f/(__expf(2.f*x) + 1.f); }

#define HST 264   // h LDS row stride (256 + 8 pad)

// Load one 4-tile B-fragment batch: buf[g] <- seg[tile(g)=g*16+w][kt]
// address (elements): g*65536 + kt*512 + (w*4096 + lane*8)
#define LOADB(buf, seg, nkt) { \
  buf[0] = ld8(seg + (0*65536 + (nkt)*512) + wvoff); \
  buf[1] = ld8(seg + (1*65536 + (nkt)*512) + wvoff); \
  buf[2] = ld8(seg + (2*65536 + (nkt)*512) + wvoff); \
  buf[3] = ld8(seg + (3*65536 + (nkt)*512) + wvoff); }

#define MFMAB(afrag, buf) { \
  acc0 = mfma16(afrag, buf[0], acc0); \
  acc1 = mfma16(afrag, buf[1], acc1); \
  acc2 = mfma16(afrag, buf[2], acc2); \
  acc3 = mfma16(afrag, buf[3], acc3); }

__global__ __launch_bounds__(1024) void lstm_fused(
    const float* __restrict__ latent,
    const float* __restrict__ b_lh, const float* __restrict__ b_lc,
    const float* __restrict__ b_ih0, const float* __restrict__ b_hh0,
    const float* __restrict__ b_ih1, const float* __restrict__ b_hh1,
    const float* __restrict__ b_out,
    const u16* __restrict__ ws,
    float* __restrict__ out)
{
  __shared__ __attribute__((aligned(16))) u16 lat_s[16*136];
  __shared__ __attribute__((aligned(16))) u16 h0_s[2][16*HST];
  __shared__ __attribute__((aligned(16))) u16 h1_s[2][16*HST];

  const u16* __restrict__ w_lh  = ws + OFF_LH;
  const u16* __restrict__ w_lc  = ws + OFF_LC;
  const u16* __restrict__ w_ih0 = ws + OFF_IH0;
  const u16* __restrict__ w_hh0 = ws + OFF_HH0;
  const u16* __restrict__ w_ih1 = ws + OFF_IH1;
  const u16* __restrict__ w_hh1 = ws + OFF_HH1;
  const u16* __restrict__ w_out = ws + OFF_OUT;

  const int tid  = threadIdx.x;
  const int w    = tid >> 6;      // wave 0..15
  const int lane = tid & 63;
  const int col  = lane & 15;
  const int quad = lane >> 4;
  const int bbase = blockIdx.x * 16;
  const int hrow  = quad * 4;
  const int l8    = lane * 8;
  const int wvoff = w * 4096 + l8;          // per-wave base offset into KB=8 matrices
  const int hread = col * HST + quad * 8;   // A-fragment LDS read base

  // ---- stage latent (bf16) ----
  for (int i = tid; i < 16*128; i += 1024){
    int b = i >> 7, k = i & 127;
    lat_s[b*136 + k] = f2bf(latent[(bbase + b)*128 + k]);
  }
  __syncthreads();

  bf16x8 latA[4];
  #pragma unroll
  for (int kt = 0; kt < 4; ++kt)
    latA[kt] = ld8(&lat_s[col*136 + kt*32 + quad*8]);

  // ---- gx0 (4 tiles per wave, kept in regs) + bias1 ----
  f32x4 gx0[4];
  float bias1[4];
  #pragma unroll
  for (int g = 0; g < 4; ++g){
    const int nt = g*16 + w;
    const int n  = nt*16 + col;
    float bias = b_ih0[n] + b_hh0[n];
    f32x4 a = {bias, bias, bias, bias};
    #pragma unroll
    for (int kt = 0; kt < 4; ++kt)
      a = mfma16(latA[kt], ld8(w_ih0 + ((nt*4 + kt) << 9) + l8), a);
    gx0[g] = a;
    bias1[g] = b_ih1[n] + b_hh1[n];
  }

  // ---- initial h/c (wave owns h-tile w of layer0, tile 16+w of layer1) ----
  // "step -1" outputs go to buffer index 1 (in-loop: step t -> buffer t&1).
  float c0[4], c1[4];
  {
    const int n0 = w*16 + col;
    { float bias = b_lc[n0]; f32x4 a = {bias,bias,bias,bias};
      #pragma unroll
      for (int kt=0;kt<4;++kt) a = mfma16(latA[kt], ld8(w_lc + ((w*4+kt)<<9) + l8), a);
      #pragma unroll
      for (int r=0;r<4;++r) c0[r] = a[r]; }
    { float bias = b_lc[256 + n0]; f32x4 a = {bias,bias,bias,bias};
      #pragma unroll
      for (int kt=0;kt<4;++kt) a = mfma16(latA[kt], ld8(w_lc + (((16+w)*4+kt)<<9) + l8), a);
      #pragma unroll
      for (int r=0;r<4;++r) c1[r] = a[r]; }
    { float bias = b_lh[n0]; f32x4 a = {bias,bias,bias,bias};
      #pragma unroll
      for (int kt=0;kt<4;++kt) a = mfma16(latA[kt], ld8(w_lh + ((w*4+kt)<<9) + l8), a);
      #pragma unroll
      for (int r=0;r<4;++r) h0_s[1][(hrow+r)*HST + w*16 + col] = f2bf(a[r]); }
    { float bias = b_lh[256 + n0]; f32x4 a = {bias,bias,bias,bias};
      #pragma unroll
      for (int kt=0;kt<4;++kt) a = mfma16(latA[kt], ld8(w_lh + (((16+w)*4+kt)<<9) + l8), a);
      #pragma unroll
      for (int r=0;r<4;++r) h1_s[1][(hrow+r)*HST + w*16 + col] = f2bf(a[r]); }
  }
  const float bout = (w < 4) ? b_out[w*16 + col] : 0.f;

  __syncthreads();

  bf16x8 h0A[8];
  #pragma unroll
  for (int kt=0;kt<8;++kt) h0A[kt] = ld8(&h0_s[1][hread + kt*32]);

  bf16x8 Pa[4], Pb[4];
  LOADB(Pa, w_hh0, 0);   // prologue prefetch

  for (int t = 0; t < 256; ++t){
    u16* h0c = h0_s[t & 1];
    u16* h1c = h1_s[t & 1];
    const u16* h1p = h1_s[(t & 1) ^ 1];   // h1(t-1)

    // ======== layer 0: gates = gx0 + h0(t-1) @ w_hh0^T ========
    f32x4 acc0 = gx0[0], acc1 = gx0[1], acc2 = gx0[2], acc3 = gx0[3];
    LOADB(Pb, w_hh0, 1);  MFMAB(h0A[0], Pa);
    LOADB(Pa, w_hh0, 2);  MFMAB(h0A[1], Pb);
    LOADB(Pb, w_hh0, 3);  MFMAB(h0A[2], Pa);
    LOADB(Pa, w_hh0, 4);  MFMAB(h0A[3], Pb);
    LOADB(Pb, w_hh0, 5);  MFMAB(h0A[4], Pa);
    LOADB(Pa, w_hh0, 6);  MFMAB(h0A[5], Pb);
    LOADB(Pb, w_hh0, 7);  MFMAB(h0A[6], Pa);
    LOADB(Pa, w_ih1, 0);  MFMAB(h0A[7], Pb);

    #pragma unroll
    for (int r=0;r<4;++r){
      float ii = sigm(acc0[r]);
      float ff = sigm(acc1[r]);
      float gg = tanh_f(acc2[r]);
      float oo = sigm(acc3[r]);
      float c = ff*c0[r] + ii*gg;
      c0[r] = c;
      h0c[(hrow+r)*HST + w*16 + col] = f2bf(oo * tanh_f(c));
    }
    __syncthreads();   // bar1: h0(t) visible
    #pragma unroll
    for (int kt=0;kt<8;++kt) h0A[kt] = ld8(&h0c[hread + kt*32]);

    // ======== layer 1: bias1 + h0(t)@w_ih1^T + h1(t-1)@w_hh1^T ========
    acc0 = (f32x4){bias1[0],bias1[0],bias1[0],bias1[0]};
    acc1 = (f32x4){bias1[1],bias1[1],bias1[1],bias1[1]};
    acc2 = (f32x4){bias1[2],bias1[2],bias1[2],bias1[2]};
    acc3 = (f32x4){bias1[3],bias1[3],bias1[3],bias1[3]};
    LOADB(Pb, w_ih1, 1);  MFMAB(h0A[0], Pa);
    LOADB(Pa, w_ih1, 2);  MFMAB(h0A[1], Pb);
    LOADB(Pb, w_ih1, 3);  MFMAB(h0A[2], Pa);
    LOADB(Pa, w_ih1, 4);  MFMAB(h0A[3], Pb);
    LOADB(Pb, w_ih1, 5);  MFMAB(h0A[4], Pa);
    LOADB(Pa, w_ih1, 6);  MFMAB(h0A[5], Pb);
    LOADB(Pb, w_ih1, 7);  MFMAB(h0A[6], Pa);
    LOADB(Pa, w_hh1, 0);  MFMAB(h0A[7], Pb);

    bf16x8 a1;
    a1 = ld8(&h1p[hread + 0*32]); LOADB(Pb, w_hh1, 1);  MFMAB(a1, Pa);
    a1 = ld8(&h1p[hread + 1*32]); LOADB(Pa, w_hh1, 2);  MFMAB(a1, Pb);
    a1 = ld8(&h1p[hread + 2*32]); LOADB(Pb, w_hh1, 3);  MFMAB(a1, Pa);
    a1 = ld8(&h1p[hread + 3*32]); LOADB(Pa, w_hh1, 4);  MFMAB(a1, Pb);
    a1 = ld8(&h1p[hread + 4*32]); LOADB(Pb, w_hh1, 5);  MFMAB(a1, Pa);
    a1 = ld8(&h1p[hread + 5*32]); LOADB(Pa, w_hh1, 6);  MFMAB(a1, Pb);
    a1 = ld8(&h1p[hread + 6*32]); LOADB(Pb, w_hh1, 7);  MFMAB(a1, Pa);
    a1 = ld8(&h1p[hread + 7*32]); LOADB(Pa, w_hh0, 0);  MFMAB(a1, Pb);  // prefetch next step

    #pragma unroll
    for (int r=0;r<4;++r){
      float ii = sigm(acc0[r]);
      float ff = sigm(acc1[r]);
      float gg = tanh_f(acc2[r]);
      float oo = sigm(acc3[r]);
      float c = ff*c1[r] + ii*gg;
      c1[r] = c;
      h1c[(hrow+r)*HST + w*16 + col] = f2bf(oo * tanh_f(c));
    }
    __syncthreads();   // bar2: h1(t) visible

    // ======== output projection (waves 0..3) ========
    if (w < 4){
      f32x4 oacc = {bout, bout, bout, bout};
      #pragma unroll
      for (int kt=0;kt<8;++kt){
        bf16x8 af = ld8(&h1c[hread + kt*32]);
        oacc = mfma16(af, ld8(w_out + ((w*8 + kt) << 9) + l8), oacc);
      }
      const int o = w*16 + col;
      #pragma unroll
      for (int r=0;r<4;++r){
        int b = bbase + hrow + r;
        out[(b*256 + t)*64 + o] = oacc[r];
      }
    }
  }
}

extern "C" void kernel_launch(void* const* d_in, const int* in_sizes, int n_in,
                              void* d_out, int out_size, void* d_ws, size_t ws_size,
                              hipStream_t stream)
{
  (void)in_sizes; (void)n_in; (void)out_size; (void)ws_size;
  const float* latent = (const float*)d_in[0];
  const float* w_lh   = (const float*)d_in[1];
  const float* b_lh   = (const float*)d_in[2];
  const float* w_lc   = (const float*)d_in[3];
  const float* b_lc   = (const float*)d_in[4];
  const float* w_ih0  = (const float*)d_in[5];
  const float* w_hh0  = (const float*)d_in[6];
  const float* b_ih0  = (const float*)d_in[7];
  const float* b_hh0  = (const float*)d_in[8];
  const float* w_ih1  = (const float*)d_in[9];
  const float* w_hh1  = (const float*)d_in[10];
  const float* b_ih1  = (const float*)d_in[11];
  const float* b_hh1  = (const float*)d_in[12];
  const float* w_out  = (const float*)d_in[13];
  const float* b_out  = (const float*)d_in[14];
  u16* ws = (u16*)d_ws;
  float* out = (float*)d_out;

  auto cvt = [&](const float* src, int off, int ntiles, int kbshift){
    int n = ntiles << (kbshift + 9);
    convert_swizzle<<<dim3((n + 255)/256), dim3(256), 0, stream>>>(src, ws + off, ntiles, kbshift);
  };
  cvt(w_lh,  OFF_LH,  32, 2);
  cvt(w_lc,  OFF_LC,  32, 2);
  cvt(w_ih0, OFF_IH0, 64, 2);
  cvt(w_hh0, OFF_HH0, 64, 3);
  cvt(w_ih1, OFF_IH1, 64, 3);
  cvt(w_hh1, OFF_HH1, 64, 3);
  cvt(w_out, OFF_OUT, 4, 3);

  lstm_fused<<<dim3(64), dim3(1024), 0, stream>>>(latent, b_lh, b_lc, b_ih0, b_hh0,
                                                  b_ih1, b_hh1, b_out, ws, out);
}

// Round 5
// 10923.441 us; speedup vs baseline: 2.3580x; 1.0601x over previous
//
#include <hip/hip_runtime.h>

// LSTMDecoder: B=1024, L=128, H=256, OUT=64, T=256, 2 layers.
// R5: 64 WGs x 1024 threads (16 waves, 4 waves/SIMD). Wave w owns gate tiles
// {g*16+w}. Weight loads in a 3-deep ping-pong (Pa/Pb/Pc, 12 KB in flight
// per wave); A-fragments re-read from LDS per batch (no persistent h0A) to
// keep live VGPRs ~110. __launch_bounds__(1024, 4) pins 4 waves/EU -> 128
// VGPR budget (R4's default budget was 64 -> compiler serialized the
// pipeline with vmcnt waits per batch; 108k cyc/step ~ 96 loads x full
// latency). Barriers stay plain __syncthreads (R3's lgkm-only asm barrier
// raced). Per-WG per-step weight stream = 1.57 MB bf16.

typedef float f32x4 __attribute__((ext_vector_type(4)));
typedef short bf16x8 __attribute__((ext_vector_type(8)));
typedef unsigned short u16;

// bf16 workspace layout (element offsets), swizzled:
// elem[((nt*KB + kt)*64 + lane)*8 + j] = W[nt*16 + (lane&15)][kt*32 + (lane>>4)*8 + j]
#define OFF_LH   0          // 32 tiles, KB=4
#define OFF_LC   65536      // 32 tiles, KB=4
#define OFF_IH0  131072     // 64 tiles, KB=4
#define OFF_HH0  262144     // 64 tiles, KB=8
#define OFF_IH1  524288     // 64 tiles, KB=8
#define OFF_HH1  786432     // 64 tiles, KB=8
#define OFF_OUT  1048576    // 4 tiles,  KB=8

__device__ __forceinline__ u16 f2bf(float x){
  unsigned u = __builtin_bit_cast(unsigned, x);
  return (u16)((u + 0x7fffu + ((u >> 16) & 1u)) >> 16);  // RNE
}

__global__ __launch_bounds__(256) void convert_swizzle(
    const float* __restrict__ src, u16* __restrict__ dst,
    int ntiles, int kbshift)
{
  int idx = blockIdx.x * 256 + threadIdx.x;
  int kblocks = 1 << kbshift;
  int n = ntiles << (kbshift + 9);
  if (idx >= n) return;
  int j    = idx & 7;
  int lane = (idx >> 3) & 63;
  int t3   = idx >> 9;
  int kt   = t3 & (kblocks - 1);
  int nt   = t3 >> kbshift;
  int row  = nt * 16 + (lane & 15);
  int k    = kt * 32 + (lane >> 4) * 8 + j;
  dst[idx] = f2bf(src[row * (kblocks * 32) + k]);
}

__device__ __forceinline__ f32x4 mfma16(bf16x8 a, bf16x8 b, f32x4 c){
  return __builtin_amdgcn_mfma_f32_16x16x32_bf16(a, b, c, 0, 0, 0);
}
__device__ __forceinline__ bf16x8 ld8(const u16* p){ return *(const bf16x8*)p; }
__device__ __forceinline__ float sigm(float x){ return 1.f/(1.f + __expf(-x)); }
__device__ __forceinline__ float tanh_f(float x){ return 1.f - 2.f/(__expf(2.f*x) + 1.f); }

#define HST 264   // h LDS row stride (256 + 8 pad)

// Load one 4-tile B-fragment batch: buf[g] <- seg[tile(g)=g*16+w][kt]
#define LOADB(buf, seg, nkt) { \
  buf[0] = ld8(seg + (0*65536 + (nkt)*512) + wvoff); \
  buf[1] = ld8(seg + (1*65536 + (nkt)*512) + wvoff); \
  buf[2] = ld8(seg + (2*65536 + (nkt)*512) + wvoff); \
  buf[3] = ld8(seg + (3*65536 + (nkt)*512) + wvoff); }

#define MFMAB(afrag, buf) { \
  acc0 = mfma16(afrag, buf[0], acc0); \
  acc1 = mfma16(afrag, buf[1], acc1); \
  acc2 = mfma16(afrag, buf[2], acc2); \
  acc3 = mfma16(afrag, buf[3], acc3); }

__global__ __launch_bounds__(1024, 4) void lstm_fused(
    const float* __restrict__ latent,
    const float* __restrict__ b_lh, const float* __restrict__ b_lc,
    const float* __restrict__ b_ih0, const float* __restrict__ b_hh0,
    const float* __restrict__ b_ih1, const float* __restrict__ b_hh1,
    const float* __restrict__ b_out,
    const u16* __restrict__ ws,
    float* __restrict__ out)
{
  __shared__ __attribute__((aligned(16))) u16 lat_s[16*136];
  __shared__ __attribute__((aligned(16))) u16 h0_s[2][16*HST];
  __shared__ __attribute__((aligned(16))) u16 h1_s[2][16*HST];

  const u16* __restrict__ w_lh  = ws + OFF_LH;
  const u16* __restrict__ w_lc  = ws + OFF_LC;
  const u16* __restrict__ w_ih0 = ws + OFF_IH0;
  const u16* __restrict__ w_hh0 = ws + OFF_HH0;
  const u16* __restrict__ w_ih1 = ws + OFF_IH1;
  const u16* __restrict__ w_hh1 = ws + OFF_HH1;
  const u16* __restrict__ w_out = ws + OFF_OUT;

  const int tid  = threadIdx.x;
  const int w    = tid >> 6;      // wave 0..15
  const int lane = tid & 63;
  const int col  = lane & 15;
  const int quad = lane >> 4;
  const int bbase = blockIdx.x * 16;
  const int hrow  = quad * 4;
  const int l8    = lane * 8;
  const int wvoff = w * 4096 + l8;          // per-wave base offset into KB=8 matrices
  const int hread = col * HST + quad * 8;   // A-fragment LDS read base

  // ---- stage latent (bf16) ----
  for (int i = tid; i < 16*128; i += 1024){
    int b = i >> 7, k = i & 127;
    lat_s[b*136 + k] = f2bf(latent[(bbase + b)*128 + k]);
  }
  __syncthreads();

  bf16x8 latA[4];
  #pragma unroll
  for (int kt = 0; kt < 4; ++kt)
    latA[kt] = ld8(&lat_s[col*136 + kt*32 + quad*8]);

  // ---- gx0 (4 tiles per wave, kept in regs) + bias1 ----
  f32x4 gx0[4];
  float bias1[4];
  #pragma unroll
  for (int g = 0; g < 4; ++g){
    const int nt = g*16 + w;
    const int n  = nt*16 + col;
    float bias = b_ih0[n] + b_hh0[n];
    f32x4 a = {bias, bias, bias, bias};
    #pragma unroll
    for (int kt = 0; kt < 4; ++kt)
      a = mfma16(latA[kt], ld8(w_ih0 + ((nt*4 + kt) << 9) + l8), a);
    gx0[g] = a;
    bias1[g] = b_ih1[n] + b_hh1[n];
  }

  // ---- initial h/c ("step -1" h goes to buffer 1; step t uses buffer t&1) ----
  float c0[4], c1[4];
  {
    const int n0 = w*16 + col;
    { float bias = b_lc[n0]; f32x4 a = {bias,bias,bias,bias};
      #pragma unroll
      for (int kt=0;kt<4;++kt) a = mfma16(latA[kt], ld8(w_lc + ((w*4+kt)<<9) + l8), a);
      #pragma unroll
      for (int r=0;r<4;++r) c0[r] = a[r]; }
    { float bias = b_lc[256 + n0]; f32x4 a = {bias,bias,bias,bias};
      #pragma unroll
      for (int kt=0;kt<4;++kt) a = mfma16(latA[kt], ld8(w_lc + (((16+w)*4+kt)<<9) + l8), a);
      #pragma unroll
      for (int r=0;r<4;++r) c1[r] = a[r]; }
    { float bias = b_lh[n0]; f32x4 a = {bias,bias,bias,bias};
      #pragma unroll
      for (int kt=0;kt<4;++kt) a = mfma16(latA[kt], ld8(w_lh + ((w*4+kt)<<9) + l8), a);
      #pragma unroll
      for (int r=0;r<4;++r) h0_s[1][(hrow+r)*HST + w*16 + col] = f2bf(a[r]); }
    { float bias = b_lh[256 + n0]; f32x4 a = {bias,bias,bias,bias};
      #pragma unroll
      for (int kt=0;kt<4;++kt) a = mfma16(latA[kt], ld8(w_lh + (((16+w)*4+kt)<<9) + l8), a);
      #pragma unroll
      for (int r=0;r<4;++r) h1_s[1][(hrow+r)*HST + w*16 + col] = f2bf(a[r]); }
  }
  const float bout = (w < 4) ? b_out[w*16 + col] : 0.f;

  __syncthreads();

  bf16x8 Pa[4], Pb[4], Pc[4];
  LOADB(Pa, w_hh0, 0);   // prologue: 2 batches in flight
  LOADB(Pb, w_hh0, 1);

  for (int t = 0; t < 256; ++t){
    const u16* h0p = h0_s[(t & 1) ^ 1];   // h0(t-1)
    u16*       h0c = h0_s[t & 1];
    const u16* h1p = h1_s[(t & 1) ^ 1];   // h1(t-1)
    u16*       h1c = h1_s[t & 1];
    bf16x8 a0;

    // ======== layer 0: gates = gx0 + h0(t-1) @ w_hh0^T ========
    f32x4 acc0 = gx0[0], acc1 = gx0[1], acc2 = gx0[2], acc3 = gx0[3];
    a0 = ld8(&h0p[hread + 0*32]); LOADB(Pc, w_hh0, 2); MFMAB(a0, Pa);
    a0 = ld8(&h0p[hread + 1*32]); LOADB(Pa, w_hh0, 3); MFMAB(a0, Pb);
    a0 = ld8(&h0p[hread + 2*32]); LOADB(Pb, w_hh0, 4); MFMAB(a0, Pc);
    a0 = ld8(&h0p[hread + 3*32]); LOADB(Pc, w_hh0, 5); MFMAB(a0, Pa);
    a0 = ld8(&h0p[hread + 4*32]); LOADB(Pa, w_hh0, 6); MFMAB(a0, Pb);
    a0 = ld8(&h0p[hread + 5*32]); LOADB(Pb, w_hh0, 7); MFMAB(a0, Pc);
    a0 = ld8(&h0p[hread + 6*32]); LOADB(Pc, w_ih1, 0); MFMAB(a0, Pa);
    a0 = ld8(&h0p[hread + 7*32]); LOADB(Pa, w_ih1, 1); MFMAB(a0, Pb);

    #pragma unroll
    for (int r=0;r<4;++r){
      float ii = sigm(acc0[r]);
      float ff = sigm(acc1[r]);
      float gg = tanh_f(acc2[r]);
      float oo = sigm(acc3[r]);
      float c = ff*c0[r] + ii*gg;
      c0[r] = c;
      h0c[(hrow+r)*HST + w*16 + col] = f2bf(oo * tanh_f(c));
    }
    __syncthreads();   // bar1: h0(t) visible

    // ======== layer 1: bias1 + h0(t)@w_ih1^T + h1(t-1)@w_hh1^T ========
    acc0 = (f32x4){bias1[0],bias1[0],bias1[0],bias1[0]};
    acc1 = (f32x4){bias1[1],bias1[1],bias1[1],bias1[1]};
    acc2 = (f32x4){bias1[2],bias1[2],bias1[2],bias1[2]};
    acc3 = (f32x4){bias1[3],bias1[3],bias1[3],bias1[3]};
    a0 = ld8(&h0c[hread + 0*32]); LOADB(Pb, w_ih1, 2); MFMAB(a0, Pc);
    a0 = ld8(&h0c[hread + 1*32]); LOADB(Pc, w_ih1, 3); MFMAB(a0, Pa);
    a0 = ld8(&h0c[hread + 2*32]); LOADB(Pa, w_ih1, 4); MFMAB(a0, Pb);
    a0 = ld8(&h0c[hread + 3*32]); LOADB(Pb, w_ih1, 5); MFMAB(a0, Pc);
    a0 = ld8(&h0c[hread + 4*32]); LOADB(Pc, w_ih1, 6); MFMAB(a0, Pa);
    a0 = ld8(&h0c[hread + 5*32]); LOADB(Pa, w_ih1, 7); MFMAB(a0, Pb);
    a0 = ld8(&h0c[hread + 6*32]); LOADB(Pb, w_hh1, 0); MFMAB(a0, Pc);
    a0 = ld8(&h0c[hread + 7*32]); LOADB(Pc, w_hh1, 1); MFMAB(a0, Pa);

    a0 = ld8(&h1p[hread + 0*32]); LOADB(Pa, w_hh1, 2); MFMAB(a0, Pb);
    a0 = ld8(&h1p[hread + 1*32]); LOADB(Pb, w_hh1, 3); MFMAB(a0, Pc);
    a0 = ld8(&h1p[hread + 2*32]); LOADB(Pc, w_hh1, 4); MFMAB(a0, Pa);
    a0 = ld8(&h1p[hread + 3*32]); LOADB(Pa, w_hh1, 5); MFMAB(a0, Pb);
    a0 = ld8(&h1p[hread + 4*32]); LOADB(Pb, w_hh1, 6); MFMAB(a0, Pc);
    a0 = ld8(&h1p[hread + 5*32]); LOADB(Pc, w_hh1, 7); MFMAB(a0, Pa);
    a0 = ld8(&h1p[hread + 6*32]); LOADB(Pa, w_hh0, 0); MFMAB(a0, Pb);  // next-step prefetch
    a0 = ld8(&h1p[hread + 7*32]); LOADB(Pb, w_hh0, 1); MFMAB(a0, Pc);  // next-step prefetch

    #pragma unroll
    for (int r=0;r<4;++r){
      float ii = sigm(acc0[r]);
      float ff = sigm(acc1[r]);
      float gg = tanh_f(acc2[r]);
      float oo = sigm(acc3[r]);
      float c = ff*c1[r] + ii*gg;
      c1[r] = c;
      h1c[(hrow+r)*HST + w*16 + col] = f2bf(oo * tanh_f(c));
    }
    __syncthreads();   // bar2: h1(t) visible

    // ======== output projection (waves 0..3) ========
    if (w < 4){
      f32x4 oacc = {bout, bout, bout, bout};
      #pragma unroll
      for (int kt=0;kt<8;++kt){
        bf16x8 af = ld8(&h1c[hread + kt*32]);
        oacc = mfma16(af, ld8(w_out + ((w*8 + kt) << 9) + l8), oacc);
      }
      const int o = w*16 + col;
      #pragma unroll
      for (int r=0;r<4;++r){
        int b = bbase + hrow + r;
        out[(b*256 + t)*64 + o] = oacc[r];
      }
    }
  }
}

extern "C" void kernel_launch(void* const* d_in, const int* in_sizes, int n_in,
                              void* d_out, int out_size, void* d_ws, size_t ws_size,
                              hipStream_t stream)
{
  (void)in_sizes; (void)n_in; (void)out_size; (void)ws_size;
  const float* latent = (const float*)d_in[0];
  const float* w_lh   = (const float*)d_in[1];
  const float* b_lh   = (const float*)d_in[2];
  const float* w_lc   = (const float*)d_in[3];
  const float* b_lc   = (const float*)d_in[4];
  const float* w_ih0  = (const float*)d_in[5];
  const float* w_hh0  = (const float*)d_in[6];
  const float* b_ih0  = (const float*)d_in[7];
  const float* b_hh0  = (const float*)d_in[8];
  const float* w_ih1  = (const float*)d_in[9];
  const float* w_hh1  = (const float*)d_in[10];
  const float* b_ih1  = (const float*)d_in[11];
  const float* b_hh1  = (const float*)d_in[12];
  const float* w_out  = (const float*)d_in[13];
  const float* b_out  = (const float*)d_in[14];
  u16* ws = (u16*)d_ws;
  float* out = (float*)d_out;

  auto cvt = [&](const float* src, int off, int ntiles, int kbshift){
    int n = ntiles << (kbshift + 9);
    convert_swizzle<<<dim3((n + 255)/256), dim3(256), 0, stream>>>(src, ws + off, ntiles, kbshift);
  };
  cvt(w_lh,  OFF_LH,  32, 2);
  cvt(w_lc,  OFF_LC,  32, 2);
  cvt(w_ih0, OFF_IH0, 64, 2);
  cvt(w_hh0, OFF_HH0, 64, 3);
  cvt(w_ih1, OFF_IH1, 64, 3);
  cvt(w_hh1, OFF_HH1, 64, 3);
  cvt(w_out, OFF_OUT, 4, 3);

  lstm_fused<<<dim3(64), dim3(1024), 0, stream>>>(latent, b_lh, b_lc, b_ih0, b_hh0,
                                                  b_ih1, b_hh1, b_out, ws, out);
}

// Round 6
// 10907.637 us; speedup vs baseline: 2.3614x; 1.0014x over previous
//
#include <hip/hip_runtime.h>

// LSTMDecoder: B=1024, L=128, H=256, OUT=64, T=256, 2 layers.
// R6: 64 WGs x 1024 threads (16 waves, 4 waves/SIMD). Wave w owns gate tiles
// {g*16+w}. 3-deep ping-pong weight pipeline (Pa/Pb/Pc). KEY FIX vs R5:
// amdgpu_waves_per_eu(4,4) — R4/R5 the allocator squeezed to 64 VGPR to
// enable 8 waves/EU (2 blocks/CU) that our 64-block grid can never use,
// which destroyed the pipeline (3 buffers alone need 48 VGPR). Pinning
// max=4 waves/EU frees the 128-VGPR budget. Also: nontemporal out-stores
// so the 64 MB output stream stops evicting the 2.1 MB L2-resident weights
// (FETCH_SIZE showed 45% of the weight stream falling through to HBM).
// Barriers stay plain __syncthreads (R3's lgkm-only asm barrier raced).

typedef float f32x4 __attribute__((ext_vector_type(4)));
typedef short bf16x8 __attribute__((ext_vector_type(8)));
typedef unsigned short u16;

// bf16 workspace layout (element offsets), swizzled:
// elem[((nt*KB + kt)*64 + lane)*8 + j] = W[nt*16 + (lane&15)][kt*32 + (lane>>4)*8 + j]
#define OFF_LH   0          // 32 tiles, KB=4
#define OFF_LC   65536      // 32 tiles, KB=4
#define OFF_IH0  131072     // 64 tiles, KB=4
#define OFF_HH0  262144     // 64 tiles, KB=8
#define OFF_IH1  524288     // 64 tiles, KB=8
#define OFF_HH1  786432     // 64 tiles, KB=8
#define OFF_OUT  1048576    // 4 tiles,  KB=8

__device__ __forceinline__ u16 f2bf(float x){
  unsigned u = __builtin_bit_cast(unsigned, x);
  return (u16)((u + 0x7fffu + ((u >> 16) & 1u)) >> 16);  // RNE
}

__global__ __launch_bounds__(256) void convert_swizzle(
    const float* __restrict__ src, u16* __restrict__ dst,
    int ntiles, int kbshift)
{
  int idx = blockIdx.x * 256 + threadIdx.x;
  int kblocks = 1 << kbshift;
  int n = ntiles << (kbshift + 9);
  if (idx >= n) return;
  int j    = idx & 7;
  int lane = (idx >> 3) & 63;
  int t3   = idx >> 9;
  int kt   = t3 & (kblocks - 1);
  int nt   = t3 >> kbshift;
  int row  = nt * 16 + (lane & 15);
  int k    = kt * 32 + (lane >> 4) * 8 + j;
  dst[idx] = f2bf(src[row * (kblocks * 32) + k]);
}

__device__ __forceinline__ f32x4 mfma16(bf16x8 a, bf16x8 b, f32x4 c){
  return __builtin_amdgcn_mfma_f32_16x16x32_bf16(a, b, c, 0, 0, 0);
}
__device__ __forceinline__ bf16x8 ld8(const u16* p){ return *(const bf16x8*)p; }
__device__ __forceinline__ float sigm(float x){ return 1.f/(1.f + __expf(-x)); }
__device__ __forceinline__ float tanh_f(float x){ return 1.f - 2.f/(__expf(2.f*x) + 1.f); }

#define HST 264   // h LDS row stride (256 + 8 pad)

// Load one 4-tile B-fragment batch: buf[g] <- seg[tile(g)=g*16+w][kt]
#define LOADB(buf, seg, nkt) { \
  buf[0] = ld8(seg + (0*65536 + (nkt)*512) + wvoff); \
  buf[1] = ld8(seg + (1*65536 + (nkt)*512) + wvoff); \
  buf[2] = ld8(seg + (2*65536 + (nkt)*512) + wvoff); \
  buf[3] = ld8(seg + (3*65536 + (nkt)*512) + wvoff); }

#define MFMAB(afrag, buf) { \
  acc0 = mfma16(afrag, buf[0], acc0); \
  acc1 = mfma16(afrag, buf[1], acc1); \
  acc2 = mfma16(afrag, buf[2], acc2); \
  acc3 = mfma16(afrag, buf[3], acc3); }

__global__ __launch_bounds__(1024)
__attribute__((amdgpu_waves_per_eu(4, 4)))
void lstm_fused(
    const float* __restrict__ latent,
    const float* __restrict__ b_lh, const float* __restrict__ b_lc,
    const float* __restrict__ b_ih0, const float* __restrict__ b_hh0,
    const float* __restrict__ b_ih1, const float* __restrict__ b_hh1,
    const float* __restrict__ b_out,
    const u16* __restrict__ ws,
    float* __restrict__ out)
{
  __shared__ __attribute__((aligned(16))) u16 lat_s[16*136];
  __shared__ __attribute__((aligned(16))) u16 h0_s[2][16*HST];
  __shared__ __attribute__((aligned(16))) u16 h1_s[2][16*HST];

  const u16* __restrict__ w_lh  = ws + OFF_LH;
  const u16* __restrict__ w_lc  = ws + OFF_LC;
  const u16* __restrict__ w_ih0 = ws + OFF_IH0;
  const u16* __restrict__ w_hh0 = ws + OFF_HH0;
  const u16* __restrict__ w_ih1 = ws + OFF_IH1;
  const u16* __restrict__ w_hh1 = ws + OFF_HH1;
  const u16* __restrict__ w_out = ws + OFF_OUT;

  const int tid  = threadIdx.x;
  const int w    = tid >> 6;      // wave 0..15
  const int lane = tid & 63;
  const int col  = lane & 15;
  const int quad = lane >> 4;
  const int bbase = blockIdx.x * 16;
  const int hrow  = quad * 4;
  const int l8    = lane * 8;
  const int wvoff = w * 4096 + l8;          // per-wave base offset into KB=8 matrices
  const int hread = col * HST + quad * 8;   // A-fragment LDS read base

  // ---- stage latent (bf16) ----
  for (int i = tid; i < 16*128; i += 1024){
    int b = i >> 7, k = i & 127;
    lat_s[b*136 + k] = f2bf(latent[(bbase + b)*128 + k]);
  }
  __syncthreads();

  bf16x8 latA[4];
  #pragma unroll
  for (int kt = 0; kt < 4; ++kt)
    latA[kt] = ld8(&lat_s[col*136 + kt*32 + quad*8]);

  // ---- gx0 (4 tiles per wave, kept in regs) + bias1 ----
  f32x4 gx0[4];
  float bias1[4];
  #pragma unroll
  for (int g = 0; g < 4; ++g){
    const int nt = g*16 + w;
    const int n  = nt*16 + col;
    float bias = b_ih0[n] + b_hh0[n];
    f32x4 a = {bias, bias, bias, bias};
    #pragma unroll
    for (int kt = 0; kt < 4; ++kt)
      a = mfma16(latA[kt], ld8(w_ih0 + ((nt*4 + kt) << 9) + l8), a);
    gx0[g] = a;
    bias1[g] = b_ih1[n] + b_hh1[n];
  }

  // ---- initial h/c ("step -1" h goes to buffer 1; step t uses buffer t&1) ----
  float c0[4], c1[4];
  {
    const int n0 = w*16 + col;
    { float bias = b_lc[n0]; f32x4 a = {bias,bias,bias,bias};
      #pragma unroll
      for (int kt=0;kt<4;++kt) a = mfma16(latA[kt], ld8(w_lc + ((w*4+kt)<<9) + l8), a);
      #pragma unroll
      for (int r=0;r<4;++r) c0[r] = a[r]; }
    { float bias = b_lc[256 + n0]; f32x4 a = {bias,bias,bias,bias};
      #pragma unroll
      for (int kt=0;kt<4;++kt) a = mfma16(latA[kt], ld8(w_lc + (((16+w)*4+kt)<<9) + l8), a);
      #pragma unroll
      for (int r=0;r<4;++r) c1[r] = a[r]; }
    { float bias = b_lh[n0]; f32x4 a = {bias,bias,bias,bias};
      #pragma unroll
      for (int kt=0;kt<4;++kt) a = mfma16(latA[kt], ld8(w_lh + ((w*4+kt)<<9) + l8), a);
      #pragma unroll
      for (int r=0;r<4;++r) h0_s[1][(hrow+r)*HST + w*16 + col] = f2bf(a[r]); }
    { float bias = b_lh[256 + n0]; f32x4 a = {bias,bias,bias,bias};
      #pragma unroll
      for (int kt=0;kt<4;++kt) a = mfma16(latA[kt], ld8(w_lh + (((16+w)*4+kt)<<9) + l8), a);
      #pragma unroll
      for (int r=0;r<4;++r) h1_s[1][(hrow+r)*HST + w*16 + col] = f2bf(a[r]); }
  }
  const float bout = (w < 4) ? b_out[w*16 + col] : 0.f;

  __syncthreads();

  bf16x8 Pa[4], Pb[4], Pc[4];
  LOADB(Pa, w_hh0, 0);   // prologue: 2 batches in flight
  LOADB(Pb, w_hh0, 1);

  for (int t = 0; t < 256; ++t){
    const u16* h0p = h0_s[(t & 1) ^ 1];   // h0(t-1)
    u16*       h0c = h0_s[t & 1];
    const u16* h1p = h1_s[(t & 1) ^ 1];   // h1(t-1)
    u16*       h1c = h1_s[t & 1];
    bf16x8 a0;

    // ======== layer 0: gates = gx0 + h0(t-1) @ w_hh0^T ========
    f32x4 acc0 = gx0[0], acc1 = gx0[1], acc2 = gx0[2], acc3 = gx0[3];
    a0 = ld8(&h0p[hread + 0*32]); LOADB(Pc, w_hh0, 2); MFMAB(a0, Pa);
    a0 = ld8(&h0p[hread + 1*32]); LOADB(Pa, w_hh0, 3); MFMAB(a0, Pb);
    a0 = ld8(&h0p[hread + 2*32]); LOADB(Pb, w_hh0, 4); MFMAB(a0, Pc);
    a0 = ld8(&h0p[hread + 3*32]); LOADB(Pc, w_hh0, 5); MFMAB(a0, Pa);
    a0 = ld8(&h0p[hread + 4*32]); LOADB(Pa, w_hh0, 6); MFMAB(a0, Pb);
    a0 = ld8(&h0p[hread + 5*32]); LOADB(Pb, w_hh0, 7); MFMAB(a0, Pc);
    a0 = ld8(&h0p[hread + 6*32]); LOADB(Pc, w_ih1, 0); MFMAB(a0, Pa);
    a0 = ld8(&h0p[hread + 7*32]); LOADB(Pa, w_ih1, 1); MFMAB(a0, Pb);

    #pragma unroll
    for (int r=0;r<4;++r){
      float ii = sigm(acc0[r]);
      float ff = sigm(acc1[r]);
      float gg = tanh_f(acc2[r]);
      float oo = sigm(acc3[r]);
      float c = ff*c0[r] + ii*gg;
      c0[r] = c;
      h0c[(hrow+r)*HST + w*16 + col] = f2bf(oo * tanh_f(c));
    }
    __syncthreads();   // bar1: h0(t) visible

    // ======== layer 1: bias1 + h0(t)@w_ih1^T + h1(t-1)@w_hh1^T ========
    acc0 = (f32x4){bias1[0],bias1[0],bias1[0],bias1[0]};
    acc1 = (f32x4){bias1[1],bias1[1],bias1[1],bias1[1]};
    acc2 = (f32x4){bias1[2],bias1[2],bias1[2],bias1[2]};
    acc3 = (f32x4){bias1[3],bias1[3],bias1[3],bias1[3]};
    a0 = ld8(&h0c[hread + 0*32]); LOADB(Pb, w_ih1, 2); MFMAB(a0, Pc);
    a0 = ld8(&h0c[hread + 1*32]); LOADB(Pc, w_ih1, 3); MFMAB(a0, Pa);
    a0 = ld8(&h0c[hread + 2*32]); LOADB(Pa, w_ih1, 4); MFMAB(a0, Pb);
    a0 = ld8(&h0c[hread + 3*32]); LOADB(Pb, w_ih1, 5); MFMAB(a0, Pc);
    a0 = ld8(&h0c[hread + 4*32]); LOADB(Pc, w_ih1, 6); MFMAB(a0, Pa);
    a0 = ld8(&h0c[hread + 5*32]); LOADB(Pa, w_ih1, 7); MFMAB(a0, Pb);
    a0 = ld8(&h0c[hread + 6*32]); LOADB(Pb, w_hh1, 0); MFMAB(a0, Pc);
    a0 = ld8(&h0c[hread + 7*32]); LOADB(Pc, w_hh1, 1); MFMAB(a0, Pa);

    a0 = ld8(&h1p[hread + 0*32]); LOADB(Pa, w_hh1, 2); MFMAB(a0, Pb);
    a0 = ld8(&h1p[hread + 1*32]); LOADB(Pb, w_hh1, 3); MFMAB(a0, Pc);
    a0 = ld8(&h1p[hread + 2*32]); LOADB(Pc, w_hh1, 4); MFMAB(a0, Pa);
    a0 = ld8(&h1p[hread + 3*32]); LOADB(Pa, w_hh1, 5); MFMAB(a0, Pb);
    a0 = ld8(&h1p[hread + 4*32]); LOADB(Pb, w_hh1, 6); MFMAB(a0, Pc);
    a0 = ld8(&h1p[hread + 5*32]); LOADB(Pc, w_hh1, 7); MFMAB(a0, Pa);
    a0 = ld8(&h1p[hread + 6*32]); LOADB(Pa, w_hh0, 0); MFMAB(a0, Pb);  // next-step prefetch
    a0 = ld8(&h1p[hread + 7*32]); LOADB(Pb, w_hh0, 1); MFMAB(a0, Pc);  // next-step prefetch

    #pragma unroll
    for (int r=0;r<4;++r){
      float ii = sigm(acc0[r]);
      float ff = sigm(acc1[r]);
      float gg = tanh_f(acc2[r]);
      float oo = sigm(acc3[r]);
      float c = ff*c1[r] + ii*gg;
      c1[r] = c;
      h1c[(hrow+r)*HST + w*16 + col] = f2bf(oo * tanh_f(c));
    }
    __syncthreads();   // bar2: h1(t) visible

    // ======== output projection (waves 0..3), nontemporal stores ========
    if (w < 4){
      f32x4 oacc = {bout, bout, bout, bout};
      #pragma unroll
      for (int kt=0;kt<8;++kt){
        bf16x8 af = ld8(&h1c[hread + kt*32]);
        oacc = mfma16(af, ld8(w_out + ((w*8 + kt) << 9) + l8), oacc);
      }
      const int o = w*16 + col;
      #pragma unroll
      for (int r=0;r<4;++r){
        int b = bbase + hrow + r;
        __builtin_nontemporal_store(oacc[r], &out[(b*256 + t)*64 + o]);
      }
    }
  }
}

extern "C" void kernel_launch(void* const* d_in, const int* in_sizes, int n_in,
                              void* d_out, int out_size, void* d_ws, size_t ws_size,
                              hipStream_t stream)
{
  (void)in_sizes; (void)n_in; (void)out_size; (void)ws_size;
  const float* latent = (const float*)d_in[0];
  const float* w_lh   = (const float*)d_in[1];
  const float* b_lh   = (const float*)d_in[2];
  const float* w_lc   = (const float*)d_in[3];
  const float* b_lc   = (const float*)d_in[4];
  const float* w_ih0  = (const float*)d_in[5];
  const float* w_hh0  = (const float*)d_in[6];
  const float* b_ih0  = (const float*)d_in[7];
  const float* b_hh0  = (const float*)d_in[8];
  const float* w_ih1  = (const float*)d_in[9];
  const float* w_hh1  = (const float*)d_in[10];
  const float* b_ih1  = (const float*)d_in[11];
  const float* b_hh1  = (const float*)d_in[12];
  const float* w_out  = (const float*)d_in[13];
  const float* b_out  = (const float*)d_in[14];
  u16* ws = (u16*)d_ws;
  float* out = (float*)d_out;

  auto cvt = [&](const float* src, int off, int ntiles, int kbshift){
    int n = ntiles << (kbshift + 9);
    convert_swizzle<<<dim3((n + 255)/256), dim3(256), 0, stream>>>(src, ws + off, ntiles, kbshift);
  };
  cvt(w_lh,  OFF_LH,  32, 2);
  cvt(w_lc,  OFF_LC,  32, 2);
  cvt(w_ih0, OFF_IH0, 64, 2);
  cvt(w_hh0, OFF_HH0, 64, 3);
  cvt(w_ih1, OFF_IH1, 64, 3);
  cvt(w_hh1, OFF_HH1, 64, 3);
  cvt(w_out, OFF_OUT, 4, 3);

  lstm_fused<<<dim3(64), dim3(1024), 0, stream>>>(latent, b_lh, b_lc, b_ih0, b_hh0,
                                                  b_ih1, b_hh1, b_out, ws, out);
}

// Round 8
// 9444.224 us; speedup vs baseline: 2.7273x; 1.1550x over previous
//
#include <hip/hip_runtime.h>

// LSTMDecoder: B=1024, L=128, H=256, OUT=64, T=256, 2 layers.
// R8: weight streaming via __builtin_amdgcn_global_load_lds (no VGPR dest,
// so the pre-RA scheduler can't serialize it — R4-R6 showed reg-destined
// load pipelines collapse at VGPR=64). 16 waves x 8KB staging, 2 slots of
// 4KB (one kt x 4 gate tiles). R7 BUG FIX: R7 issued chunk i+2 into slot
// i&1 BEFORE consuming chunk i from it — DMA could land early and corrupt
// (absmax 0.43). Order is now WAITV4 (chunk i landed; only chunk i+1 newer)
// -> consume (ds_read+MFMA) -> lgkmcnt(0) (slot dead) -> issue chunk i+2.
// Max 2 chunks in flight/wave; 128 KB/CU aggregate covers ~600cyc latency.
// Barriers: plain __syncthreads (R3's lgkm-only asm barrier raced).

typedef float f32x4 __attribute__((ext_vector_type(4)));
typedef short bf16x8 __attribute__((ext_vector_type(8)));
typedef unsigned short u16;
typedef unsigned int u32;

// bf16 workspace layout (element offsets), swizzled:
// elem[((nt*KB + kt)*64 + lane)*8 + j] = W[nt*16 + (lane&15)][kt*32 + (lane>>4)*8 + j]
#define OFF_LH   0          // 32 tiles, KB=4
#define OFF_LC   65536      // 32 tiles, KB=4
#define OFF_IH0  131072     // 64 tiles, KB=4
#define OFF_HH0  262144     // 64 tiles, KB=8
#define OFF_IH1  524288     // 64 tiles, KB=8
#define OFF_HH1  786432     // 64 tiles, KB=8
#define OFF_OUT  1048576    // 4 tiles,  KB=8

__device__ __forceinline__ u16 f2bf(float x){
  unsigned u = __builtin_bit_cast(unsigned, x);
  return (u16)((u + 0x7fffu + ((u >> 16) & 1u)) >> 16);  // RNE
}

__global__ __launch_bounds__(256) void convert_swizzle(
    const float* __restrict__ src, u16* __restrict__ dst,
    int ntiles, int kbshift)
{
  int idx = blockIdx.x * 256 + threadIdx.x;
  int kblocks = 1 << kbshift;
  int n = ntiles << (kbshift + 9);
  if (idx >= n) return;
  int j    = idx & 7;
  int lane = (idx >> 3) & 63;
  int t3   = idx >> 9;
  int kt   = t3 & (kblocks - 1);
  int nt   = t3 >> kbshift;
  int row  = nt * 16 + (lane & 15);
  int k    = kt * 32 + (lane >> 4) * 8 + j;
  dst[idx] = f2bf(src[row * (kblocks * 32) + k]);
}

__device__ __forceinline__ f32x4 mfma16(bf16x8 a, bf16x8 b, f32x4 c){
  return __builtin_amdgcn_mfma_f32_16x16x32_bf16(a, b, c, 0, 0, 0);
}
__device__ __forceinline__ bf16x8 ld8(const u16* p){ return *(const bf16x8*)p; }
__device__ __forceinline__ float sigm(float x){ return 1.f/(1.f + __expf(-x)); }
__device__ __forceinline__ float tanh_f(float x){ return 1.f - 2.f/(__expf(2.f*x) + 1.f); }

// global(16B/lane) -> LDS DMA. LDS dest is wave-uniform base; lane i lands
// at base + i*16B. Global ptr is per-lane.
__device__ __forceinline__ void gll16(const u16* g, u16* l){
  __builtin_amdgcn_global_load_lds(
      (const __attribute__((address_space(1))) u32*)g,
      (__attribute__((address_space(3))) u32*)l, 16, 0, 0);
}

// s_waitcnt vmcnt(4): <=4 vm ops outstanding -> the 4 newest (chunk i+1) may
// be in flight, everything older (chunk i, stores) has completed.
// imm: vmcnt lo[3:0]=4, expcnt[6:4]=7, lgkmcnt[11:8]=15, vmcnt hi[15:14]=0.
#define WAITV4()  { __builtin_amdgcn_s_waitcnt(0xF74); __asm__ __volatile__("" ::: "memory"); }
// s_waitcnt lgkmcnt(0): all ds_reads complete (staging slot dead, safe to
// overwrite). vmcnt=63 (no wait): lo=0xF, hi=3 -> 0xC000|0x7F = 0xC07F.
#define WAITLGKM() { __builtin_amdgcn_s_waitcnt(0xC07F); __asm__ __volatile__("" ::: "memory"); }

#define HST 264   // h LDS row stride (256 + 8 pad)

// Issue one 4-tile chunk (kt) of `seg` into staging slot db (DMA).
#define ISSUE(seg, kt, db) { \
  u16* lb = &stg[stgw + (db)*2048]; \
  gll16(seg + 0*65536 + ((kt)*512) + wvoff, lb); \
  gll16(seg + 1*65536 + ((kt)*512) + wvoff, lb + 512); \
  gll16(seg + 2*65536 + ((kt)*512) + wvoff, lb + 1024); \
  gll16(seg + 3*65536 + ((kt)*512) + wvoff, lb + 1536); }

// Consume staging slot db against A-fragment afrag.
#define CONSUME(db, afrag) { \
  const u16* lb = &stg[stgw + (db)*2048 + l8]; \
  bf16x8 b0 = ld8(lb); bf16x8 b1 = ld8(lb + 512); \
  bf16x8 b2 = ld8(lb + 1024); bf16x8 b3 = ld8(lb + 1536); \
  acc0 = mfma16(afrag, b0, acc0); acc1 = mfma16(afrag, b1, acc1); \
  acc2 = mfma16(afrag, b2, acc2); acc3 = mfma16(afrag, b3, acc3); }

__global__ __launch_bounds__(1024)
__attribute__((amdgpu_waves_per_eu(4, 4)))
void lstm_fused(
    const float* __restrict__ latent,
    const float* __restrict__ b_lh, const float* __restrict__ b_lc,
    const float* __restrict__ b_ih0, const float* __restrict__ b_hh0,
    const float* __restrict__ b_ih1, const float* __restrict__ b_hh1,
    const float* __restrict__ b_out,
    const u16* __restrict__ ws,
    float* __restrict__ out)
{
  __shared__ __attribute__((aligned(16))) u16 stg[16*4096];     // 128 KB staging
  __shared__ __attribute__((aligned(16))) u16 h0_s[2][16*HST];  // 16.9 KB
  __shared__ __attribute__((aligned(16))) u16 h1_s[16*HST];     // 8.4 KB
  __shared__ __attribute__((aligned(16))) u16 lat_s[16*136];    // 4.3 KB

  const u16* __restrict__ w_lh  = ws + OFF_LH;
  const u16* __restrict__ w_lc  = ws + OFF_LC;
  const u16* __restrict__ w_ih0 = ws + OFF_IH0;
  const u16* __restrict__ w_hh0 = ws + OFF_HH0;
  const u16* __restrict__ w_ih1 = ws + OFF_IH1;
  const u16* __restrict__ w_hh1 = ws + OFF_HH1;
  const u16* __restrict__ w_out = ws + OFF_OUT;

  const int tid  = threadIdx.x;
  const int w    = tid >> 6;      // wave 0..15
  const int lane = tid & 63;
  const int col  = lane & 15;
  const int quad = lane >> 4;
  const int bbase = blockIdx.x * 16;
  const int hrow  = quad * 4;
  const int l8    = lane * 8;
  const int wvoff = w * 4096 + l8;          // per-wave base into KB=8 matrices
  const int hread = col * HST + quad * 8;   // A-fragment LDS read base
  const int stgw  = w * 4096;               // per-wave staging region (u16 elems)

  // ---- stage latent (bf16) ----
  for (int i = tid; i < 16*128; i += 1024){
    int b = i >> 7, k = i & 127;
    lat_s[b*136 + k] = f2bf(latent[(bbase + b)*128 + k]);
  }
  __syncthreads();

  bf16x8 latA[4];
  #pragma unroll
  for (int kt = 0; kt < 4; ++kt)
    latA[kt] = ld8(&lat_s[col*136 + kt*32 + quad*8]);

  // ---- gx0 (4 tiles per wave, kept in regs) + bias1 ----
  f32x4 gx0[4];
  float bias1[4];
  #pragma unroll
  for (int g = 0; g < 4; ++g){
    const int nt = g*16 + w;
    const int n  = nt*16 + col;
    float bias = b_ih0[n] + b_hh0[n];
    f32x4 a = {bias, bias, bias, bias};
    #pragma unroll
    for (int kt = 0; kt < 4; ++kt)
      a = mfma16(latA[kt], ld8(w_ih0 + ((nt*4 + kt) << 9) + l8), a);
    gx0[g] = a;
    bias1[g] = b_ih1[n] + b_hh1[n];
  }

  // ---- initial h/c ("step -1" h0 -> h0_s[1]; h1 -> h1_s) ----
  float c0[4], c1[4];
  {
    const int n0 = w*16 + col;
    { float bias = b_lc[n0]; f32x4 a = {bias,bias,bias,bias};
      #pragma unroll
      for (int kt=0;kt<4;++kt) a = mfma16(latA[kt], ld8(w_lc + ((w*4+kt)<<9) + l8), a);
      #pragma unroll
      for (int r=0;r<4;++r) c0[r] = a[r]; }
    { float bias = b_lc[256 + n0]; f32x4 a = {bias,bias,bias,bias};
      #pragma unroll
      for (int kt=0;kt<4;++kt) a = mfma16(latA[kt], ld8(w_lc + (((16+w)*4+kt)<<9) + l8), a);
      #pragma unroll
      for (int r=0;r<4;++r) c1[r] = a[r]; }
    { float bias = b_lh[n0]; f32x4 a = {bias,bias,bias,bias};
      #pragma unroll
      for (int kt=0;kt<4;++kt) a = mfma16(latA[kt], ld8(w_lh + ((w*4+kt)<<9) + l8), a);
      #pragma unroll
      for (int r=0;r<4;++r) h0_s[1][(hrow+r)*HST + w*16 + col] = f2bf(a[r]); }
    { float bias = b_lh[256 + n0]; f32x4 a = {bias,bias,bias,bias};
      #pragma unroll
      for (int kt=0;kt<4;++kt) a = mfma16(latA[kt], ld8(w_lh + (((16+w)*4+kt)<<9) + l8), a);
      #pragma unroll
      for (int r=0;r<4;++r) h1_s[(hrow+r)*HST + w*16 + col] = f2bf(a[r]); }
  }
  const float bout = (w < 4) ? b_out[w*16 + col] : 0.f;

  __syncthreads();

  // prologue: chunks 0,1 of w_hh0 in flight
  ISSUE(w_hh0, 0, 0);
  ISSUE(w_hh0, 1, 1);

  for (int t = 0; t < 256; ++t){
    const u16* h0p = h0_s[(t & 1) ^ 1];   // h0(t-1)
    u16*       h0c = h0_s[t & 1];

    // ======== layer 0: gates = gx0 + h0(t-1) @ w_hh0^T ========
    f32x4 acc0 = gx0[0], acc1 = gx0[1], acc2 = gx0[2], acc3 = gx0[3];
    #pragma unroll
    for (int i = 0; i < 8; ++i){
      WAITV4();                               // chunk i landed
      bf16x8 a0 = ld8(&h0p[hread + i*32]);
      CONSUME(i&1, a0);
      WAITLGKM();                             // slot i&1 dead
      if (i < 6)       ISSUE(w_hh0, i+2, i&1)
      else if (i == 6) ISSUE(w_ih1, 0, 0)
      else             ISSUE(w_ih1, 1, 1)
    }

    #pragma unroll
    for (int r=0;r<4;++r){
      float ii = sigm(acc0[r]);
      float ff = sigm(acc1[r]);
      float gg = tanh_f(acc2[r]);
      float oo = sigm(acc3[r]);
      float c = ff*c0[r] + ii*gg;
      c0[r] = c;
      h0c[(hrow+r)*HST + w*16 + col] = f2bf(oo * tanh_f(c));
    }
    __syncthreads();   // bar1: h0(t) visible (drains vmcnt; staged chunks land, stay valid)

    // ======== layer 1: bias1 + h0(t)@w_ih1^T + h1(t-1)@w_hh1^T ========
    acc0 = (f32x4){bias1[0],bias1[0],bias1[0],bias1[0]};
    acc1 = (f32x4){bias1[1],bias1[1],bias1[1],bias1[1]};
    acc2 = (f32x4){bias1[2],bias1[2],bias1[2],bias1[2]};
    acc3 = (f32x4){bias1[3],bias1[3],bias1[3],bias1[3]};
    #pragma unroll
    for (int i = 0; i < 8; ++i){
      WAITV4();
      bf16x8 a0 = ld8(&h0c[hread + i*32]);
      CONSUME(i&1, a0);
      WAITLGKM();
      if (i < 6)       ISSUE(w_ih1, i+2, i&1)
      else if (i == 6) ISSUE(w_hh1, 0, 0)
      else             ISSUE(w_hh1, 1, 1)
    }
    #pragma unroll
    for (int i = 0; i < 8; ++i){
      WAITV4();
      bf16x8 a0 = ld8(&h1_s[hread + i*32]);   // h1(t-1), single buffer
      CONSUME(i&1, a0);
      WAITLGKM();
      if (i < 6)       ISSUE(w_hh1, i+2, i&1)
      else if (i == 6) ISSUE(w_hh0, 0, 0)     // next-step prefetch
      else             ISSUE(w_hh0, 1, 1)     // next-step prefetch
    }
    __syncthreads();   // bar2a: all h1(t-1) reads done before overwrite

    #pragma unroll
    for (int r=0;r<4;++r){
      float ii = sigm(acc0[r]);
      float ff = sigm(acc1[r]);
      float gg = tanh_f(acc2[r]);
      float oo = sigm(acc3[r]);
      float c = ff*c1[r] + ii*gg;
      c1[r] = c;
      h1_s[(hrow+r)*HST + w*16 + col] = f2bf(oo * tanh_f(c));
    }
    __syncthreads();   // bar2b: h1(t) visible

    // ======== output projection (waves 0..3), nontemporal stores ========
    if (w < 4){
      f32x4 oacc = {bout, bout, bout, bout};
      #pragma unroll
      for (int kt=0;kt<8;++kt){
        bf16x8 af = ld8(&h1_s[hread + kt*32]);
        oacc = mfma16(af, ld8(w_out + ((w*8 + kt) << 9) + l8), oacc);
      }
      const int o = w*16 + col;
      #pragma unroll
      for (int r=0;r<4;++r){
        int b = bbase + hrow + r;
        __builtin_nontemporal_store(oacc[r], &out[(b*256 + t)*64 + o]);
      }
    }
  }
}

extern "C" void kernel_launch(void* const* d_in, const int* in_sizes, int n_in,
                              void* d_out, int out_size, void* d_ws, size_t ws_size,
                              hipStream_t stream)
{
  (void)in_sizes; (void)n_in; (void)out_size; (void)ws_size;
  const float* latent = (const float*)d_in[0];
  const float* w_lh   = (const float*)d_in[1];
  const float* b_lh   = (const float*)d_in[2];
  const float* w_lc   = (const float*)d_in[3];
  const float* b_lc   = (const float*)d_in[4];
  const float* w_ih0  = (const float*)d_in[5];
  const float* w_hh0  = (const float*)d_in[6];
  const float* b_ih0  = (const float*)d_in[7];
  const float* b_hh0  = (const float*)d_in[8];
  const float* w_ih1  = (const float*)d_in[9];
  const float* w_hh1  = (const float*)d_in[10];
  const float* b_ih1  = (const float*)d_in[11];
  const float* b_hh1  = (const float*)d_in[12];
  const float* w_out  = (const float*)d_in[13];
  const float* b_out  = (const float*)d_in[14];
  u16* ws = (u16*)d_ws;
  float* out = (float*)d_out;

  auto cvt = [&](const float* src, int off, int ntiles, int kbshift){
    int n = ntiles << (kbshift + 9);
    convert_swizzle<<<dim3((n + 255)/256), dim3(256), 0, stream>>>(src, ws + off, ntiles, kbshift);
  };
  cvt(w_lh,  OFF_LH,  32, 2);
  cvt(w_lc,  OFF_LC,  32, 2);
  cvt(w_ih0, OFF_IH0, 64, 2);
  cvt(w_hh0, OFF_HH0, 64, 3);
  cvt(w_ih1, OFF_IH1, 64, 3);
  cvt(w_hh1, OFF_HH1, 64, 3);
  cvt(w_out, OFF_OUT, 4, 3);

  lstm_fused<<<dim3(64), dim3(1024), 0, stream>>>(latent, b_lh, b_lc, b_ih0, b_hh0,
                                                  b_ih1, b_hh1, b_out, ws, out);
}

// Round 9
// 4221.670 us; speedup vs baseline: 6.1013x; 2.2371x over previous
//
#include <hip/hip_runtime.h>

// LSTMDecoder: B=1024, L=128, H=256, OUT=64, T=256, 2 layers.
// R9: weight streaming via inline-asm global_load_dwordx4 pipeline.
// History: R4-R6 showed compiler serializes register-destined load pipelines
// (VGPR pinned at 64, ~650cyc/load). R8's global_load_lds DMA fixed that but
// hit the DMA's per-op throughput wall (~40-60 cyc/op/CU; 1536 ops/step = 84k
// cyc ~= measured 88k). Fix: asm volatile loads ("=&v" outputs) + asm
// s_waitcnt vmcnt(4) taking the values as "+v" operands — scheduler cannot
// reorder/sink, RA must keep 8 loads (32 VGPR) in flight. Normal loads have
// ~4x the per-op throughput of DMA (~16cyc/KB). Weights never touch LDS.
// Within phase loops the vm queue holds only my asm loads (h traffic is
// lgkm), so vmcnt(4) == "chunk i landed". __syncthreads drains vmcnt at
// phase ends (correct, few-hundred-cyc cost). Floor ~12us/step ~= 3.1ms.

typedef float f32x4 __attribute__((ext_vector_type(4)));
typedef short bf16x8 __attribute__((ext_vector_type(8)));
typedef unsigned short u16;
typedef unsigned int u32;

// bf16 workspace layout (element offsets), swizzled:
// elem[((nt*KB + kt)*64 + lane)*8 + j] = W[nt*16 + (lane&15)][kt*32 + (lane>>4)*8 + j]
#define OFF_LH   0          // 32 tiles, KB=4
#define OFF_LC   65536      // 32 tiles, KB=4
#define OFF_IH0  131072     // 64 tiles, KB=4
#define OFF_HH0  262144     // 64 tiles, KB=8
#define OFF_IH1  524288     // 64 tiles, KB=8
#define OFF_HH1  786432     // 64 tiles, KB=8
#define OFF_OUT  1048576    // 4 tiles,  KB=8

__device__ __forceinline__ u16 f2bf(float x){
  unsigned u = __builtin_bit_cast(unsigned, x);
  return (u16)((u + 0x7fffu + ((u >> 16) & 1u)) >> 16);  // RNE
}

__global__ __launch_bounds__(256) void convert_swizzle(
    const float* __restrict__ src, u16* __restrict__ dst,
    int ntiles, int kbshift)
{
  int idx = blockIdx.x * 256 + threadIdx.x;
  int kblocks = 1 << kbshift;
  int n = ntiles << (kbshift + 9);
  if (idx >= n) return;
  int j    = idx & 7;
  int lane = (idx >> 3) & 63;
  int t3   = idx >> 9;
  int kt   = t3 & (kblocks - 1);
  int nt   = t3 >> kbshift;
  int row  = nt * 16 + (lane & 15);
  int k    = kt * 32 + (lane >> 4) * 8 + j;
  dst[idx] = f2bf(src[row * (kblocks * 32) + k]);
}

__device__ __forceinline__ f32x4 mfma16(bf16x8 a, bf16x8 b, f32x4 c){
  return __builtin_amdgcn_mfma_f32_16x16x32_bf16(a, b, c, 0, 0, 0);
}
__device__ __forceinline__ bf16x8 ld8(const u16* p){ return *(const bf16x8*)p; }
__device__ __forceinline__ float sigm(float x){ return 1.f/(1.f + __expf(-x)); }
__device__ __forceinline__ float tanh_f(float x){ return 1.f - 2.f/(__expf(2.f*x) + 1.f); }

#define HST 264   // h LDS row stride (256 + 8 pad)

// Issue 4 tile-fragment loads (chunk = one kt, 4 gate tiles) into Q[0..3].
// saddr form: 32-bit VGPR byte offset + SGPR-pair base. Volatile => ordered
// vs other asm; "=&v" => RA reserves 4 VGPRs/load until last use.
#define ISSUE4(Q, seg, kt) \
  asm volatile( \
    "global_load_dwordx4 %0, %4, %8\n\t" \
    "global_load_dwordx4 %1, %5, %8\n\t" \
    "global_load_dwordx4 %2, %6, %8\n\t" \
    "global_load_dwordx4 %3, %7, %8" \
    : "=&v"(Q[0]), "=&v"(Q[1]), "=&v"(Q[2]), "=&v"(Q[3]) \
    : "v"(voffW +           (u32)((kt)*1024)), \
      "v"(voffW + 131072u + (u32)((kt)*1024)), \
      "v"(voffW + 262144u + (u32)((kt)*1024)), \
      "v"(voffW + 393216u + (u32)((kt)*1024)), \
      "s"(seg) \
    : "memory")

// Wait until <=4 vm ops outstanding (the newer chunk), i.e. chunk in Q has
// landed. "+v" ties Q through the block so every use orders after the wait.
#define WAITC(Q) \
  asm volatile("s_waitcnt vmcnt(4)" \
    : "+v"(Q[0]), "+v"(Q[1]), "+v"(Q[2]), "+v"(Q[3]) :: "memory")

#define MFMA4(afrag, Q) { \
  acc0 = mfma16(afrag, Q[0], acc0); \
  acc1 = mfma16(afrag, Q[1], acc1); \
  acc2 = mfma16(afrag, Q[2], acc2); \
  acc3 = mfma16(afrag, Q[3], acc3); }

__global__ __launch_bounds__(1024)
__attribute__((amdgpu_waves_per_eu(4, 4)))
void lstm_fused(
    const float* __restrict__ latent,
    const float* __restrict__ b_lh, const float* __restrict__ b_lc,
    const float* __restrict__ b_ih0, const float* __restrict__ b_hh0,
    const float* __restrict__ b_ih1, const float* __restrict__ b_hh1,
    const float* __restrict__ b_out,
    const u16* __restrict__ ws,
    float* __restrict__ out)
{
  __shared__ __attribute__((aligned(16))) u16 h0_s[2][16*HST];  // 16.9 KB
  __shared__ __attribute__((aligned(16))) u16 h1_s[16*HST];     // 8.4 KB
  __shared__ __attribute__((aligned(16))) u16 lat_s[16*136];    // 4.3 KB

  const u16* __restrict__ w_lh  = ws + OFF_LH;
  const u16* __restrict__ w_lc  = ws + OFF_LC;
  const u16* __restrict__ w_ih0 = ws + OFF_IH0;
  const u16* __restrict__ w_hh0 = ws + OFF_HH0;
  const u16* __restrict__ w_ih1 = ws + OFF_IH1;
  const u16* __restrict__ w_hh1 = ws + OFF_HH1;
  const u16* __restrict__ w_out = ws + OFF_OUT;

  const int tid  = threadIdx.x;
  const int w    = tid >> 6;      // wave 0..15
  const int lane = tid & 63;
  const int col  = lane & 15;
  const int quad = lane >> 4;
  const int bbase = blockIdx.x * 16;
  const int hrow  = quad * 4;
  const int l8    = lane * 8;
  const u32 voffW = (u32)(w * 8192 + lane * 16);  // per-wave byte base into KB=8 matrices
  const int hread = col * HST + quad * 8;         // A-fragment LDS read base

  // ---- stage latent (bf16) ----
  for (int i = tid; i < 16*128; i += 1024){
    int b = i >> 7, k = i & 127;
    lat_s[b*136 + k] = f2bf(latent[(bbase + b)*128 + k]);
  }
  __syncthreads();

  bf16x8 latA[4];
  #pragma unroll
  for (int kt = 0; kt < 4; ++kt)
    latA[kt] = ld8(&lat_s[col*136 + kt*32 + quad*8]);

  // ---- gx0 (4 tiles per wave, kept in regs) + bias1 ----
  f32x4 gx0[4];
  float bias1[4];
  #pragma unroll
  for (int g = 0; g < 4; ++g){
    const int nt = g*16 + w;
    const int n  = nt*16 + col;
    float bias = b_ih0[n] + b_hh0[n];
    f32x4 a = {bias, bias, bias, bias};
    #pragma unroll
    for (int kt = 0; kt < 4; ++kt)
      a = mfma16(latA[kt], ld8(w_ih0 + ((nt*4 + kt) << 9) + l8), a);
    gx0[g] = a;
    bias1[g] = b_ih1[n] + b_hh1[n];
  }

  // ---- initial h/c ("step -1" h0 -> h0_s[1]; h1 -> h1_s) ----
  float c0[4], c1[4];
  {
    const int n0 = w*16 + col;
    { float bias = b_lc[n0]; f32x4 a = {bias,bias,bias,bias};
      #pragma unroll
      for (int kt=0;kt<4;++kt) a = mfma16(latA[kt], ld8(w_lc + ((w*4+kt)<<9) + l8), a);
      #pragma unroll
      for (int r=0;r<4;++r) c0[r] = a[r]; }
    { float bias = b_lc[256 + n0]; f32x4 a = {bias,bias,bias,bias};
      #pragma unroll
      for (int kt=0;kt<4;++kt) a = mfma16(latA[kt], ld8(w_lc + (((16+w)*4+kt)<<9) + l8), a);
      #pragma unroll
      for (int r=0;r<4;++r) c1[r] = a[r]; }
    { float bias = b_lh[n0]; f32x4 a = {bias,bias,bias,bias};
      #pragma unroll
      for (int kt=0;kt<4;++kt) a = mfma16(latA[kt], ld8(w_lh + ((w*4+kt)<<9) + l8), a);
      #pragma unroll
      for (int r=0;r<4;++r) h0_s[1][(hrow+r)*HST + w*16 + col] = f2bf(a[r]); }
    { float bias = b_lh[256 + n0]; f32x4 a = {bias,bias,bias,bias};
      #pragma unroll
      for (int kt=0;kt<4;++kt) a = mfma16(latA[kt], ld8(w_lh + (((16+w)*4+kt)<<9) + l8), a);
      #pragma unroll
      for (int r=0;r<4;++r) h1_s[(hrow+r)*HST + w*16 + col] = f2bf(a[r]); }
  }
  const float bout = (w < 4) ? b_out[w*16 + col] : 0.f;

  __syncthreads();

  bf16x8 Pa[4], Pb[4];
  ISSUE4(Pa, w_hh0, 0);   // prologue: 2 chunks in flight
  ISSUE4(Pb, w_hh0, 1);

  for (int t = 0; t < 256; ++t){
    const u16* h0p = h0_s[(t & 1) ^ 1];   // h0(t-1)
    u16*       h0c = h0_s[t & 1];
    bf16x8 a0;

    // ======== layer 0: gates = gx0 + h0(t-1) @ w_hh0^T ========
    f32x4 acc0 = gx0[0], acc1 = gx0[1], acc2 = gx0[2], acc3 = gx0[3];
    WAITC(Pa); a0 = ld8(&h0p[hread + 0*32]); MFMA4(a0, Pa); ISSUE4(Pa, w_hh0, 2);
    WAITC(Pb); a0 = ld8(&h0p[hread + 1*32]); MFMA4(a0, Pb); ISSUE4(Pb, w_hh0, 3);
    WAITC(Pa); a0 = ld8(&h0p[hread + 2*32]); MFMA4(a0, Pa); ISSUE4(Pa, w_hh0, 4);
    WAITC(Pb); a0 = ld8(&h0p[hread + 3*32]); MFMA4(a0, Pb); ISSUE4(Pb, w_hh0, 5);
    WAITC(Pa); a0 = ld8(&h0p[hread + 4*32]); MFMA4(a0, Pa); ISSUE4(Pa, w_hh0, 6);
    WAITC(Pb); a0 = ld8(&h0p[hread + 5*32]); MFMA4(a0, Pb); ISSUE4(Pb, w_hh0, 7);
    WAITC(Pa); a0 = ld8(&h0p[hread + 6*32]); MFMA4(a0, Pa); ISSUE4(Pa, w_ih1, 0);
    WAITC(Pb); a0 = ld8(&h0p[hread + 7*32]); MFMA4(a0, Pb); ISSUE4(Pb, w_ih1, 1);

    #pragma unroll
    for (int r=0;r<4;++r){
      float ii = sigm(acc0[r]);
      float ff = sigm(acc1[r]);
      float gg = tanh_f(acc2[r]);
      float oo = sigm(acc3[r]);
      float c = ff*c0[r] + ii*gg;
      c0[r] = c;
      h0c[(hrow+r)*HST + w*16 + col] = f2bf(oo * tanh_f(c));
    }
    __syncthreads();   // bar1: h0(t) visible (drains vmcnt; chunks land in regs, stay valid)

    // ======== layer 1: bias1 + h0(t)@w_ih1^T + h1(t-1)@w_hh1^T ========
    acc0 = (f32x4){bias1[0],bias1[0],bias1[0],bias1[0]};
    acc1 = (f32x4){bias1[1],bias1[1],bias1[1],bias1[1]};
    acc2 = (f32x4){bias1[2],bias1[2],bias1[2],bias1[2]};
    acc3 = (f32x4){bias1[3],bias1[3],bias1[3],bias1[3]};
    WAITC(Pa); a0 = ld8(&h0c[hread + 0*32]); MFMA4(a0, Pa); ISSUE4(Pa, w_ih1, 2);
    WAITC(Pb); a0 = ld8(&h0c[hread + 1*32]); MFMA4(a0, Pb); ISSUE4(Pb, w_ih1, 3);
    WAITC(Pa); a0 = ld8(&h0c[hread + 2*32]); MFMA4(a0, Pa); ISSUE4(Pa, w_ih1, 4);
    WAITC(Pb); a0 = ld8(&h0c[hread + 3*32]); MFMA4(a0, Pb); ISSUE4(Pb, w_ih1, 5);
    WAITC(Pa); a0 = ld8(&h0c[hread + 4*32]); MFMA4(a0, Pa); ISSUE4(Pa, w_ih1, 6);
    WAITC(Pb); a0 = ld8(&h0c[hread + 5*32]); MFMA4(a0, Pb); ISSUE4(Pb, w_ih1, 7);
    WAITC(Pa); a0 = ld8(&h0c[hread + 6*32]); MFMA4(a0, Pa); ISSUE4(Pa, w_hh1, 0);
    WAITC(Pb); a0 = ld8(&h0c[hread + 7*32]); MFMA4(a0, Pb); ISSUE4(Pb, w_hh1, 1);

    WAITC(Pa); a0 = ld8(&h1_s[hread + 0*32]); MFMA4(a0, Pa); ISSUE4(Pa, w_hh1, 2);
    WAITC(Pb); a0 = ld8(&h1_s[hread + 1*32]); MFMA4(a0, Pb); ISSUE4(Pb, w_hh1, 3);
    WAITC(Pa); a0 = ld8(&h1_s[hread + 2*32]); MFMA4(a0, Pa); ISSUE4(Pa, w_hh1, 4);
    WAITC(Pb); a0 = ld8(&h1_s[hread + 3*32]); MFMA4(a0, Pb); ISSUE4(Pb, w_hh1, 5);
    WAITC(Pa); a0 = ld8(&h1_s[hread + 4*32]); MFMA4(a0, Pa); ISSUE4(Pa, w_hh1, 6);
    WAITC(Pb); a0 = ld8(&h1_s[hread + 5*32]); MFMA4(a0, Pb); ISSUE4(Pb, w_hh1, 7);
    WAITC(Pa); a0 = ld8(&h1_s[hread + 6*32]); MFMA4(a0, Pa); ISSUE4(Pa, w_hh0, 0);  // next-step prefetch
    WAITC(Pb); a0 = ld8(&h1_s[hread + 7*32]); MFMA4(a0, Pb); ISSUE4(Pb, w_hh0, 1);  // next-step prefetch
    __syncthreads();   // bar2a: all h1(t-1) reads done before overwrite

    #pragma unroll
    for (int r=0;r<4;++r){
      float ii = sigm(acc0[r]);
      float ff = sigm(acc1[r]);
      float gg = tanh_f(acc2[r]);
      float oo = sigm(acc3[r]);
      float c = ff*c1[r] + ii*gg;
      c1[r] = c;
      h1_s[(hrow+r)*HST + w*16 + col] = f2bf(oo * tanh_f(c));
    }
    __syncthreads();   // bar2b: h1(t) visible

    // ======== output projection (waves 0..3), nontemporal stores ========
    if (w < 4){
      f32x4 oacc = {bout, bout, bout, bout};
      #pragma unroll
      for (int kt=0;kt<8;++kt){
        bf16x8 af = ld8(&h1_s[hread + kt*32]);
        oacc = mfma16(af, ld8(w_out + ((w*8 + kt) << 9) + l8), oacc);
      }
      const int o = w*16 + col;
      #pragma unroll
      for (int r=0;r<4;++r){
        int b = bbase + hrow + r;
        __builtin_nontemporal_store(oacc[r], &out[(b*256 + t)*64 + o]);
      }
    }
  }
}

extern "C" void kernel_launch(void* const* d_in, const int* in_sizes, int n_in,
                              void* d_out, int out_size, void* d_ws, size_t ws_size,
                              hipStream_t stream)
{
  (void)in_sizes; (void)n_in; (void)out_size; (void)ws_size;
  const float* latent = (const float*)d_in[0];
  const float* w_lh   = (const float*)d_in[1];
  const float* b_lh   = (const float*)d_in[2];
  const float* w_lc   = (const float*)d_in[3];
  const float* b_lc   = (const float*)d_in[4];
  const float* w_ih0  = (const float*)d_in[5];
  const float* w_hh0  = (const float*)d_in[6];
  const float* b_ih0  = (const float*)d_in[7];
  const float* b_hh0  = (const float*)d_in[8];
  const float* w_ih1  = (const float*)d_in[9];
  const float* w_hh1  = (const float*)d_in[10];
  const float* b_ih1  = (const float*)d_in[11];
  const float* b_hh1  = (const float*)d_in[12];
  const float* w_out  = (const float*)d_in[13];
  const float* b_out  = (const float*)d_in[14];
  u16* ws = (u16*)d_ws;
  float* out = (float*)d_out;

  auto cvt = [&](const float* src, int off, int ntiles, int kbshift){
    int n = ntiles << (kbshift + 9);
    convert_swizzle<<<dim3((n + 255)/256), dim3(256), 0, stream>>>(src, ws + off, ntiles, kbshift);
  };
  cvt(w_lh,  OFF_LH,  32, 2);
  cvt(w_lc,  OFF_LC,  32, 2);
  cvt(w_ih0, OFF_IH0, 64, 2);
  cvt(w_hh0, OFF_HH0, 64, 3);
  cvt(w_ih1, OFF_IH1, 64, 3);
  cvt(w_hh1, OFF_HH1, 64, 3);
  cvt(w_out, OFF_OUT, 4, 3);

  lstm_fused<<<dim3(64), dim3(1024), 0, stream>>>(latent, b_lh, b_lc, b_ih0, b_hh0,
                                                  b_ih1, b_hh1, b_out, ws, out);
}

// Round 10
// 4184.212 us; speedup vs baseline: 6.1559x; 1.0090x over previous
//
#include <hip/hip_runtime.h>

// LSTMDecoder: B=1024, L=128, H=256, OUT=64, T=256, 2 layers.
// R10: R9's inline-asm global_load_dwordx4 weight pipeline (defeats the
// pre-RA scheduler's load-sinking that pinned R4-R6 at ~650cyc/load), now
// depth-3 (Pa/Pb/Pc, vmcnt(8)) for 12KB/wave in flight, and h1 double-
// buffered so bar2a is gone (2 barriers/step). R9 measured 39.6k cyc/step
// vs ~27k L2-feed model (1.57MB/step at ~60B/cyc/CU); this closes the
// pipeline-slack + extra-barrier part of the gap. Weight stream is fully
// L2-resident (R9 FETCH_SIZE 11MB, HBM idle).

typedef float f32x4 __attribute__((ext_vector_type(4)));
typedef short bf16x8 __attribute__((ext_vector_type(8)));
typedef unsigned short u16;
typedef unsigned int u32;

// bf16 workspace layout (element offsets), swizzled:
// elem[((nt*KB + kt)*64 + lane)*8 + j] = W[nt*16 + (lane&15)][kt*32 + (lane>>4)*8 + j]
#define OFF_LH   0          // 32 tiles, KB=4
#define OFF_LC   65536      // 32 tiles, KB=4
#define OFF_IH0  131072     // 64 tiles, KB=4
#define OFF_HH0  262144     // 64 tiles, KB=8
#define OFF_IH1  524288     // 64 tiles, KB=8
#define OFF_HH1  786432     // 64 tiles, KB=8
#define OFF_OUT  1048576    // 4 tiles,  KB=8

__device__ __forceinline__ u16 f2bf(float x){
  unsigned u = __builtin_bit_cast(unsigned, x);
  return (u16)((u + 0x7fffu + ((u >> 16) & 1u)) >> 16);  // RNE
}

__global__ __launch_bounds__(256) void convert_swizzle(
    const float* __restrict__ src, u16* __restrict__ dst,
    int ntiles, int kbshift)
{
  int idx = blockIdx.x * 256 + threadIdx.x;
  int kblocks = 1 << kbshift;
  int n = ntiles << (kbshift + 9);
  if (idx >= n) return;
  int j    = idx & 7;
  int lane = (idx >> 3) & 63;
  int t3   = idx >> 9;
  int kt   = t3 & (kblocks - 1);
  int nt   = t3 >> kbshift;
  int row  = nt * 16 + (lane & 15);
  int k    = kt * 32 + (lane >> 4) * 8 + j;
  dst[idx] = f2bf(src[row * (kblocks * 32) + k]);
}

__device__ __forceinline__ f32x4 mfma16(bf16x8 a, bf16x8 b, f32x4 c){
  return __builtin_amdgcn_mfma_f32_16x16x32_bf16(a, b, c, 0, 0, 0);
}
__device__ __forceinline__ bf16x8 ld8(const u16* p){ return *(const bf16x8*)p; }
__device__ __forceinline__ float sigm(float x){ return 1.f/(1.f + __expf(-x)); }
__device__ __forceinline__ float tanh_f(float x){ return 1.f - 2.f/(__expf(2.f*x) + 1.f); }

#define HST 264   // h LDS row stride (256 + 8 pad)

// Issue 4 tile-fragment loads (chunk = one kt, 4 gate tiles) into Q[0..3].
#define ISSUE4(Q, seg, kt) \
  asm volatile( \
    "global_load_dwordx4 %0, %4, %8\n\t" \
    "global_load_dwordx4 %1, %5, %8\n\t" \
    "global_load_dwordx4 %2, %6, %8\n\t" \
    "global_load_dwordx4 %3, %7, %8" \
    : "=&v"(Q[0]), "=&v"(Q[1]), "=&v"(Q[2]), "=&v"(Q[3]) \
    : "v"(voffW +           (u32)((kt)*1024)), \
      "v"(voffW + 131072u + (u32)((kt)*1024)), \
      "v"(voffW + 262144u + (u32)((kt)*1024)), \
      "v"(voffW + 393216u + (u32)((kt)*1024)), \
      "s"(seg) \
    : "memory")

// Depth-3: at consume time the 2 newer chunks (8 loads) may be outstanding.
#define WAITC(Q) \
  asm volatile("s_waitcnt vmcnt(8)" \
    : "+v"(Q[0]), "+v"(Q[1]), "+v"(Q[2]), "+v"(Q[3]) :: "memory")

#define MFMA4(afrag, Q) { \
  acc0 = mfma16(afrag, Q[0], acc0); \
  acc1 = mfma16(afrag, Q[1], acc1); \
  acc2 = mfma16(afrag, Q[2], acc2); \
  acc3 = mfma16(afrag, Q[3], acc3); }

__global__ __launch_bounds__(1024)
__attribute__((amdgpu_waves_per_eu(4, 4)))
void lstm_fused(
    const float* __restrict__ latent,
    const float* __restrict__ b_lh, const float* __restrict__ b_lc,
    const float* __restrict__ b_ih0, const float* __restrict__ b_hh0,
    const float* __restrict__ b_ih1, const float* __restrict__ b_hh1,
    const float* __restrict__ b_out,
    const u16* __restrict__ ws,
    float* __restrict__ out)
{
  __shared__ __attribute__((aligned(16))) u16 h0_s[2][16*HST];  // 16.9 KB
  __shared__ __attribute__((aligned(16))) u16 h1_s[2][16*HST];  // 16.9 KB
  __shared__ __attribute__((aligned(16))) u16 lat_s[16*136];    // 4.3 KB

  const u16* __restrict__ w_lh  = ws + OFF_LH;
  const u16* __restrict__ w_lc  = ws + OFF_LC;
  const u16* __restrict__ w_ih0 = ws + OFF_IH0;
  const u16* __restrict__ w_hh0 = ws + OFF_HH0;
  const u16* __restrict__ w_ih1 = ws + OFF_IH1;
  const u16* __restrict__ w_hh1 = ws + OFF_HH1;
  const u16* __restrict__ w_out = ws + OFF_OUT;

  const int tid  = threadIdx.x;
  const int w    = tid >> 6;      // wave 0..15
  const int lane = tid & 63;
  const int col  = lane & 15;
  const int quad = lane >> 4;
  const int bbase = blockIdx.x * 16;
  const int hrow  = quad * 4;
  const int l8    = lane * 8;
  const u32 voffW = (u32)(w * 8192 + lane * 16);  // per-wave byte base into KB=8 matrices
  const int hread = col * HST + quad * 8;         // A-fragment LDS read base

  // ---- stage latent (bf16) ----
  for (int i = tid; i < 16*128; i += 1024){
    int b = i >> 7, k = i & 127;
    lat_s[b*136 + k] = f2bf(latent[(bbase + b)*128 + k]);
  }
  __syncthreads();

  bf16x8 latA[4];
  #pragma unroll
  for (int kt = 0; kt < 4; ++kt)
    latA[kt] = ld8(&lat_s[col*136 + kt*32 + quad*8]);

  // ---- gx0 (4 tiles per wave, kept in regs) + bias1 ----
  f32x4 gx0[4];
  float bias1[4];
  #pragma unroll
  for (int g = 0; g < 4; ++g){
    const int nt = g*16 + w;
    const int n  = nt*16 + col;
    float bias = b_ih0[n] + b_hh0[n];
    f32x4 a = {bias, bias, bias, bias};
    #pragma unroll
    for (int kt = 0; kt < 4; ++kt)
      a = mfma16(latA[kt], ld8(w_ih0 + ((nt*4 + kt) << 9) + l8), a);
    gx0[g] = a;
    bias1[g] = b_ih1[n] + b_hh1[n];
  }

  // ---- initial h/c ("step -1" h -> buffer 1; step t writes buffer t&1) ----
  float c0[4], c1[4];
  {
    const int n0 = w*16 + col;
    { float bias = b_lc[n0]; f32x4 a = {bias,bias,bias,bias};
      #pragma unroll
      for (int kt=0;kt<4;++kt) a = mfma16(latA[kt], ld8(w_lc + ((w*4+kt)<<9) + l8), a);
      #pragma unroll
      for (int r=0;r<4;++r) c0[r] = a[r]; }
    { float bias = b_lc[256 + n0]; f32x4 a = {bias,bias,bias,bias};
      #pragma unroll
      for (int kt=0;kt<4;++kt) a = mfma16(latA[kt], ld8(w_lc + (((16+w)*4+kt)<<9) + l8), a);
      #pragma unroll
      for (int r=0;r<4;++r) c1[r] = a[r]; }
    { float bias = b_lh[n0]; f32x4 a = {bias,bias,bias,bias};
      #pragma unroll
      for (int kt=0;kt<4;++kt) a = mfma16(latA[kt], ld8(w_lh + ((w*4+kt)<<9) + l8), a);
      #pragma unroll
      for (int r=0;r<4;++r) h0_s[1][(hrow+r)*HST + w*16 + col] = f2bf(a[r]); }
    { float bias = b_lh[256 + n0]; f32x4 a = {bias,bias,bias,bias};
      #pragma unroll
      for (int kt=0;kt<4;++kt) a = mfma16(latA[kt], ld8(w_lh + (((16+w)*4+kt)<<9) + l8), a);
      #pragma unroll
      for (int r=0;r<4;++r) h1_s[1][(hrow+r)*HST + w*16 + col] = f2bf(a[r]); }
  }
  const float bout = (w < 4) ? b_out[w*16 + col] : 0.f;

  __syncthreads();

  bf16x8 Pa[4], Pb[4], Pc[4];
  ISSUE4(Pa, w_hh0, 0);   // prologue: 3 chunks in flight
  ISSUE4(Pb, w_hh0, 1);
  ISSUE4(Pc, w_hh0, 2);

  for (int t = 0; t < 256; ++t){
    const u16* h0p = h0_s[(t & 1) ^ 1];   // h0(t-1)
    u16*       h0c = h0_s[t & 1];
    const u16* h1p = h1_s[(t & 1) ^ 1];   // h1(t-1)
    u16*       h1c = h1_s[t & 1];
    bf16x8 a0;

    // ======== layer 0: gates = gx0 + h0(t-1) @ w_hh0^T ========
    f32x4 acc0 = gx0[0], acc1 = gx0[1], acc2 = gx0[2], acc3 = gx0[3];
    WAITC(Pa); a0 = ld8(&h0p[hread + 0*32]); MFMA4(a0, Pa); ISSUE4(Pa, w_hh0, 3);
    WAITC(Pb); a0 = ld8(&h0p[hread + 1*32]); MFMA4(a0, Pb); ISSUE4(Pb, w_hh0, 4);
    WAITC(Pc); a0 = ld8(&h0p[hread + 2*32]); MFMA4(a0, Pc); ISSUE4(Pc, w_hh0, 5);
    WAITC(Pa); a0 = ld8(&h0p[hread + 3*32]); MFMA4(a0, Pa); ISSUE4(Pa, w_hh0, 6);
    WAITC(Pb); a0 = ld8(&h0p[hread + 4*32]); MFMA4(a0, Pb); ISSUE4(Pb, w_hh0, 7);
    WAITC(Pc); a0 = ld8(&h0p[hread + 5*32]); MFMA4(a0, Pc); ISSUE4(Pc, w_ih1, 0);
    WAITC(Pa); a0 = ld8(&h0p[hread + 6*32]); MFMA4(a0, Pa); ISSUE4(Pa, w_ih1, 1);
    WAITC(Pb); a0 = ld8(&h0p[hread + 7*32]); MFMA4(a0, Pb); ISSUE4(Pb, w_ih1, 2);

    #pragma unroll
    for (int r=0;r<4;++r){
      float ii = sigm(acc0[r]);
      float ff = sigm(acc1[r]);
      float gg = tanh_f(acc2[r]);
      float oo = sigm(acc3[r]);
      float c = ff*c0[r] + ii*gg;
      c0[r] = c;
      h0c[(hrow+r)*HST + w*16 + col] = f2bf(oo * tanh_f(c));
    }
    __syncthreads();   // bar1: h0(t) visible

    // ======== layer 1: bias1 + h0(t)@w_ih1^T + h1(t-1)@w_hh1^T ========
    acc0 = (f32x4){bias1[0],bias1[0],bias1[0],bias1[0]};
    acc1 = (f32x4){bias1[1],bias1[1],bias1[1],bias1[1]};
    acc2 = (f32x4){bias1[2],bias1[2],bias1[2],bias1[2]};
    acc3 = (f32x4){bias1[3],bias1[3],bias1[3],bias1[3]};
    WAITC(Pc); a0 = ld8(&h0c[hread + 0*32]); MFMA4(a0, Pc); ISSUE4(Pc, w_ih1, 3);
    WAITC(Pa); a0 = ld8(&h0c[hread + 1*32]); MFMA4(a0, Pa); ISSUE4(Pa, w_ih1, 4);
    WAITC(Pb); a0 = ld8(&h0c[hread + 2*32]); MFMA4(a0, Pb); ISSUE4(Pb, w_ih1, 5);
    WAITC(Pc); a0 = ld8(&h0c[hread + 3*32]); MFMA4(a0, Pc); ISSUE4(Pc, w_ih1, 6);
    WAITC(Pa); a0 = ld8(&h0c[hread + 4*32]); MFMA4(a0, Pa); ISSUE4(Pa, w_ih1, 7);
    WAITC(Pb); a0 = ld8(&h0c[hread + 5*32]); MFMA4(a0, Pb); ISSUE4(Pb, w_hh1, 0);
    WAITC(Pc); a0 = ld8(&h0c[hread + 6*32]); MFMA4(a0, Pc); ISSUE4(Pc, w_hh1, 1);
    WAITC(Pa); a0 = ld8(&h0c[hread + 7*32]); MFMA4(a0, Pa); ISSUE4(Pa, w_hh1, 2);

    WAITC(Pb); a0 = ld8(&h1p[hread + 0*32]); MFMA4(a0, Pb); ISSUE4(Pb, w_hh1, 3);
    WAITC(Pc); a0 = ld8(&h1p[hread + 1*32]); MFMA4(a0, Pc); ISSUE4(Pc, w_hh1, 4);
    WAITC(Pa); a0 = ld8(&h1p[hread + 2*32]); MFMA4(a0, Pa); ISSUE4(Pa, w_hh1, 5);
    WAITC(Pb); a0 = ld8(&h1p[hread + 3*32]); MFMA4(a0, Pb); ISSUE4(Pb, w_hh1, 6);
    WAITC(Pc); a0 = ld8(&h1p[hread + 4*32]); MFMA4(a0, Pc); ISSUE4(Pc, w_hh1, 7);
    WAITC(Pa); a0 = ld8(&h1p[hread + 5*32]); MFMA4(a0, Pa); ISSUE4(Pa, w_hh0, 0);  // next step
    WAITC(Pb); a0 = ld8(&h1p[hread + 6*32]); MFMA4(a0, Pb); ISSUE4(Pb, w_hh0, 1);  // next step
    WAITC(Pc); a0 = ld8(&h1p[hread + 7*32]); MFMA4(a0, Pc); ISSUE4(Pc, w_hh0, 2);  // next step

    #pragma unroll
    for (int r=0;r<4;++r){
      float ii = sigm(acc0[r]);
      float ff = sigm(acc1[r]);
      float gg = tanh_f(acc2[r]);
      float oo = sigm(acc3[r]);
      float c = ff*c1[r] + ii*gg;
      c1[r] = c;
      h1c[(hrow+r)*HST + w*16 + col] = f2bf(oo * tanh_f(c));
    }
    __syncthreads();   // bar2: h1(t) visible

    // ======== output projection (waves 0..3), nontemporal stores ========
    if (w < 4){
      f32x4 oacc = {bout, bout, bout, bout};
      #pragma unroll
      for (int kt=0;kt<8;++kt){
        bf16x8 af = ld8(&h1c[hread + kt*32]);
        oacc = mfma16(af, ld8(w_out + ((w*8 + kt) << 9) + l8), oacc);
      }
      const int o = w*16 + col;
      #pragma unroll
      for (int r=0;r<4;++r){
        int b = bbase + hrow + r;
        __builtin_nontemporal_store(oacc[r], &out[(b*256 + t)*64 + o]);
      }
    }
  }
}

extern "C" void kernel_launch(void* const* d_in, const int* in_sizes, int n_in,
                              void* d_out, int out_size, void* d_ws, size_t ws_size,
                              hipStream_t stream)
{
  (void)in_sizes; (void)n_in; (void)out_size; (void)ws_size;
  const float* latent = (const float*)d_in[0];
  const float* w_lh   = (const float*)d_in[1];
  const float* b_lh   = (const float*)d_in[2];
  const float* w_lc   = (const float*)d_in[3];
  const float* b_lc   = (const float*)d_in[4];
  const float* w_ih0  = (const float*)d_in[5];
  const float* w_hh0  = (const float*)d_in[6];
  const float* b_ih0  = (const float*)d_in[7];
  const float* b_hh0  = (const float*)d_in[8];
  const float* w_ih1  = (const float*)d_in[9];
  const float* w_hh1  = (const float*)d_in[10];
  const float* b_ih1  = (const float*)d_in[11];
  const float* b_hh1  = (const float*)d_in[12];
  const float* w_out  = (const float*)d_in[13];
  const float* b_out  = (const float*)d_in[14];
  u16* ws = (u16*)d_ws;
  float* out = (float*)d_out;

  auto cvt = [&](const float* src, int off, int ntiles, int kbshift){
    int n = ntiles << (kbshift + 9);
    convert_swizzle<<<dim3((n + 255)/256), dim3(256), 0, stream>>>(src, ws + off, ntiles, kbshift);
  };
  cvt(w_lh,  OFF_LH,  32, 2);
  cvt(w_lc,  OFF_LC,  32, 2);
  cvt(w_ih0, OFF_IH0, 64, 2);
  cvt(w_hh0, OFF_HH0, 64, 3);
  cvt(w_ih1, OFF_IH1, 64, 3);
  cvt(w_hh1, OFF_HH1, 64, 3);
  cvt(w_out, OFF_OUT, 4, 3);

  lstm_fused<<<dim3(64), dim3(1024), 0, stream>>>(latent, b_lh, b_lc, b_ih0, b_hh0,
                                                  b_ih1, b_hh1, b_out, ws, out);
}